// Round 7
// baseline (3834.298 us; speedup 1.0000x reference)
//
#include <hip/hip_runtime.h>
#include <hip/hip_cooperative_groups.h>
#include <cmath>

namespace cg = cooperative_groups;

#define NB   8
#define NPG  128
#define NN   1024
#define KNB  64
#define HD   600
#define GG   50
#define LL   6
#define WROW 640          // padded weight rows (n)
#define WCOL 640          // padded weight cols (k)
#define NKNOT 1024        // W(d) table knots over [0,10]

typedef __attribute__((ext_vector_type(8))) short short8;
typedef __attribute__((ext_vector_type(4))) short short4v;
typedef __attribute__((ext_vector_type(4))) float f32x4;

__device__ __forceinline__ short f2b(float f) {
  union { float f; unsigned u; } v; v.f = f;
  unsigned u = v.u;
  u += 0x7fffu + ((u >> 16) & 1u);
  return (short)(u >> 16);
}

__device__ __forceinline__ float b2f(unsigned us) {
  union { unsigned u; float f; } v; v.u = us << 16; return v.f;
}

__device__ __forceinline__ float ssp_fast(float x) {
  return fmaxf(x, 0.0f) + __logf(1.0f + __expf(-fabsf(x))) - 0.69314718055994531f;
}

// ---------------- merged prolog: build_graph + prep + conv_all + embed ----------------
__global__ __launch_bounds__(256) void prolog_k(
    const float* __restrict__ pos, int* __restrict__ nbr,
    float* __restrict__ dist, float* __restrict__ cval,
    const float* __restrict__ w1, short* __restrict__ basis, short* __restrict__ w1b,
    const float* __restrict__ l1w, const float* __restrict__ l2w,
    const float* __restrict__ ilw, const float* __restrict__ w2,
    short* __restrict__ nwall,
    const int* __restrict__ z, const float* __restrict__ emb,
    float* __restrict__ h, short* __restrict__ hb) {
  int bid = blockIdx.x;
  int tid = threadIdx.x;
  if (bid < 512) {
#pragma clang fp contract(off)
    __shared__ float d2s[2][128];
    __shared__ int scnt[2];
    int sub = tid >> 7;
    int j = tid & 127;
    int i = bid*2 + sub;
    int li = i & 127;
    int base = i - li;
    if (j == 0) scnt[sub] = 0;
    float px = pos[3*i], py = pos[3*i+1], pz = pos[3*i+2];
    int gj = base + j;
    float dx = px - pos[3*gj], dy = py - pos[3*gj+1], dz = pz - pos[3*gj+2];
    float d2 = dx*dx + dy*dy + dz*dz;
    bool valid = (j != li) && (d2 <= 100.0f);
    d2s[sub][j] = valid ? d2 : 3.0e38f;
    __syncthreads();
    if (valid) {
      atomicAdd(&scnt[sub], 1);
      int rank = 0;
      for (int j2 = 0; j2 < 128; ++j2) {
        float o = d2s[sub][j2];
        rank += (o < d2 || (o == d2 && j2 < j)) ? 1 : 0;
      }
      if (rank < KNB) {
        int e = i*KNB + rank;
        nbr[e] = gj;
        float d = sqrtf(d2);
        dist[e] = d;
        cval[e] = 0.5f * (cosf(d * 0.31415926535897931f) + 1.0f);
      }
    }
    __syncthreads();
    int cnt = scnt[sub]; if (cnt > KNB) cnt = KNB;
    if (j < KNB && j >= cnt) {
      int e = i*KNB + j;
      nbr[e] = i; dist[e] = 0.0f; cval[e] = 0.0f;
    }
  } else if (bid < 1728) {
    int idx = (bid - 512)*256 + tid;
    if (idx < NKNOT*64) {
      int i = idx >> 6, g = idx & 63;
      float v = 0.0f;
      if (g < GG) {
        const float step = 10.0f/49.0f;
        const float coeff = -0.5f/(step*step);
        float d = (float)i * (10.0f/(float)(NKNOT-1));
        float dd = d - step*(float)g;
        v = __expf(coeff*dd*dd);
      }
      basis[idx] = f2b(v);
    } else {
      int r = idx - NKNOT*64;
      if (r < LL*WROW*64) {
        int l = r / (WROW*64); int rem = r - l*WROW*64;
        int n = rem >> 6, k = rem & 63;
        float v = (n < HD && k < GG) ? w1[(size_t)l*GG*HD + (size_t)k*HD + n] : 0.0f;
        w1b[r] = f2b(v);
      }
    }
  } else if (bid < 4128) {
    __shared__ float T[64][65];
    int r = bid - 1728;
    int w = r / 100; int rem = r - w*100;
    int ny = rem / 10, nz = rem - ny*10;
    int kind = w / 6, l = w - kind*6;
    const float* s = (kind == 0) ? l1w : (kind == 1) ? l2w : (kind == 2) ? ilw : w2;
    s += (size_t)l*360000;
    int n0 = ny*64, k0 = nz*64;
    int ta = tid & 63, tb = tid >> 6;
    #pragma unroll
    for (int p = 0; p < 16; ++p) {
      int k = k0 + p*4 + tb;
      int n = n0 + ta;
      T[p*4 + tb][ta] = (k < HD && n < HD) ? s[(size_t)k*HD + n] : 0.0f;
    }
    __syncthreads();
    #pragma unroll
    for (int p = 0; p < 16; ++p) {
      int n = n0 + p*4 + tb;
      int k = k0 + ta;
      if (k < WCOL)
        nwall[(size_t)w*WROW*WCOL + (size_t)n*WCOL + k] = f2b(T[ta][p*4 + tb]);
    }
  } else {
    int i = bid - 4128;
    int zi = z[i];
    for (int j = tid; j < WCOL; j += 256) {
      float v = (j < HD) ? emb[(size_t)zi*HD + j] : 0.0f;
      if (j < HD) h[(size_t)i*HD + j] = v;
      hb[(size_t)i*WCOL + j] = f2b(v);
    }
  }
}

// ---------------- tabA ----------------
__global__ __launch_bounds__(256) void tabA_k(const short* __restrict__ basis,
    const short* __restrict__ w1b, const float* __restrict__ b1all,
    short* __restrict__ ttab_all) {
  const int MT = NKNOT/128;
  int l = blockIdx.x / MT;
  int mb = blockIdx.x - l*MT;
  const short* Bw = w1b + (size_t)l*WROW*64;
  short* outb = ttab_all + (size_t)l*NKNOT*WCOL;
  __shared__ __align__(16) short As[128*40];
  __shared__ __align__(16) short Bs[128*40];
  int tid = threadIdx.x;
  int lane = tid & 63, wv = tid >> 6;
  int wr = wv >> 1, wc = wv & 1;
  int col = lane & 15, quad = lane >> 4;
  int m0 = mb * 128;
  int n0 = blockIdx.y * 128;
  f32x4 acc[4][4] = {};
  for (int k0 = 0; k0 < 64; k0 += 32) {
    #pragma unroll
    for (int rep = 0; rep < 2; ++rep) {
      int s = tid + rep*256;
      int row = s >> 2, seg = s & 3;
      *(short8*)&As[row*40 + seg*8] =
          *(const short8*)(basis + (size_t)(m0 + row)*64 + k0 + seg*8);
      *(short8*)&Bs[row*40 + seg*8] =
          *(const short8*)(Bw + (size_t)(n0 + row)*64 + k0 + seg*8);
    }
    __syncthreads();
    short8 af[4], bf[4];
    #pragma unroll
    for (int mt = 0; mt < 4; ++mt)
      af[mt] = *(const short8*)&As[(wr*64 + mt*16 + col)*40 + quad*8];
    #pragma unroll
    for (int jt = 0; jt < 4; ++jt)
      bf[jt] = *(const short8*)&Bs[(wc*64 + jt*16 + col)*40 + quad*8];
    #pragma unroll
    for (int mt = 0; mt < 4; ++mt)
      #pragma unroll
      for (int jt = 0; jt < 4; ++jt)
        acc[mt][jt] = __builtin_amdgcn_mfma_f32_16x16x32_bf16(af[mt], bf[jt], acc[mt][jt], 0, 0, 0);
    __syncthreads();
  }
  #pragma unroll
  for (int jt = 0; jt < 4; ++jt) {
    int j = n0 + wc*64 + jt*16 + col;
    if (j >= WCOL) continue;
    float bj = (j < HD) ? b1all[(size_t)l*HD + j] : 0.0f;
    #pragma unroll
    for (int mt = 0; mt < 4; ++mt)
      #pragma unroll
      for (int r = 0; r < 4; ++r) {
        int row = m0 + wr*64 + mt*16 + quad*4 + r;
        short v = (j < HD) ? f2b(ssp_fast(acc[mt][jt][r] + bj)) : (short)0;
        outb[(size_t)row*WCOL + j] = v;
      }
  }
}

// ---------------- tabB ----------------
__global__ __launch_bounds__(256) void tabB_k(const short* __restrict__ ttab_all,
    const short* __restrict__ nwall, const float* __restrict__ b2all,
    short* __restrict__ wtab_b) {
  const int MT = NKNOT/128;
  int l = blockIdx.x / MT;
  int mb = blockIdx.x - l*MT;
  const short* A  = ttab_all + (size_t)l*NKNOT*WCOL;
  const short* Bw = nwall + (size_t)(18 + l)*WROW*WCOL;
  short* P = wtab_b + (size_t)l*NKNOT*HD;
  __shared__ __align__(16) short As[128*40];
  __shared__ __align__(16) short Bs[128*40];
  int tid = threadIdx.x;
  int lane = tid & 63, wv = tid >> 6;
  int wr = wv >> 1, wc = wv & 1;
  int col = lane & 15, quad = lane >> 4;
  int m0 = mb * 128;
  int n0 = blockIdx.y * 128;
  f32x4 acc[4][4] = {};
  for (int k0 = 0; k0 < WCOL; k0 += 32) {
    #pragma unroll
    for (int rep = 0; rep < 2; ++rep) {
      int s = tid + rep*256;
      int row = s >> 2, seg = s & 3;
      *(short8*)&As[row*40 + seg*8] =
          *(const short8*)(A + (size_t)(m0 + row)*WCOL + k0 + seg*8);
      *(short8*)&Bs[row*40 + seg*8] =
          *(const short8*)(Bw + (size_t)(n0 + row)*WCOL + k0 + seg*8);
    }
    __syncthreads();
    short8 af[4], bf[4];
    #pragma unroll
    for (int mt = 0; mt < 4; ++mt)
      af[mt] = *(const short8*)&As[(wr*64 + mt*16 + col)*40 + quad*8];
    #pragma unroll
    for (int jt = 0; jt < 4; ++jt)
      bf[jt] = *(const short8*)&Bs[(wc*64 + jt*16 + col)*40 + quad*8];
    #pragma unroll
    for (int mt = 0; mt < 4; ++mt)
      #pragma unroll
      for (int jt = 0; jt < 4; ++jt)
        acc[mt][jt] = __builtin_amdgcn_mfma_f32_16x16x32_bf16(af[mt], bf[jt], acc[mt][jt], 0, 0, 0);
    __syncthreads();
  }
  #pragma unroll
  for (int jt = 0; jt < 4; ++jt) {
    int j = n0 + wc*64 + jt*16 + col;
    if (j >= HD) continue;
    float bj = b2all[(size_t)l*HD + j];
    #pragma unroll
    for (int mt = 0; mt < 4; ++mt)
      #pragma unroll
      for (int r = 0; r < 4; ++r) {
        int row = m0 + wr*64 + mt*16 + quad*4 + r;
        P[(size_t)row*HD + j] = f2b(acc[mt][jt][r] + bj);
      }
  }
}

// ======== shared-memory layouts ========
struct GemmSmem {
  short As[2][2][32*72];
  short Bs[2][2][64*72];
  float red[256*8];
};
struct GatherSmem {
  float cvs[2][64]; int nbs[2][64]; int tix[2][64]; float tfr[2][64];
};
struct PoolSmem { float red[8][64]; };

// ---------------- gemm phase: 32x64 tile at (m0,n0), 2-way split-K, BK=64, 5 steps ----------------
template<int MODE>
__device__ __forceinline__ void gemm_phase(const short* __restrict__ A,
    const short* __restrict__ Bw, const float* __restrict__ bias,
    short* __restrict__ outb, float* __restrict__ hacc,
    int m0, int n0, char* smem_raw) {
  GemmSmem* S = (GemmSmem*)smem_raw;
  int tid = threadIdx.x;
  int g = tid >> 8;
  int t = tid & 255;
  int lane = t & 63, wv = t >> 6;
  int col = lane & 15, quad = lane >> 4;
  int ar = t >> 3, aseg = (t & 7)*8;
  int br = t >> 2, bseg = (t & 3)*16;
  const int kb = g * 320;
  const short* Aptr = A  + (size_t)(m0 + ar)*WCOL + kb + aseg;
  const short* Bptr = Bw + (size_t)(n0 + br)*WCOL + kb + bseg;
  f32x4 acc[2] = {};
  {
    short8 a0 = *(const short8*)Aptr;
    short8 b0 = *(const short8*)Bptr;
    short8 b1 = *(const short8*)(Bptr + 8);
    *(short8*)&S->As[g][0][ar*72 + aseg] = a0;
    *(short8*)&S->Bs[g][0][br*72 + bseg] = b0;
    *(short8*)&S->Bs[g][0][br*72 + bseg + 8] = b1;
  }
  __syncthreads();
  for (int kk = 0; kk < 5; ++kk) {
    int cur = kk & 1, nxt = cur ^ 1;
    short8 a_n, b_n0, b_n1;
    if (kk < 4) {
      a_n  = *(const short8*)(Aptr + (kk + 1)*64);
      b_n0 = *(const short8*)(Bptr + (kk + 1)*64);
      b_n1 = *(const short8*)(Bptr + (kk + 1)*64 + 8);
    }
    #pragma unroll
    for (int kh = 0; kh < 2; ++kh) {
      short8 bf = *(const short8*)&S->Bs[g][cur][(wv*16 + col)*72 + kh*32 + quad*8];
      #pragma unroll
      for (int mt = 0; mt < 2; ++mt) {
        short8 af = *(const short8*)&S->As[g][cur][(mt*16 + col)*72 + kh*32 + quad*8];
        acc[mt] = __builtin_amdgcn_mfma_f32_16x16x32_bf16(af, bf, acc[mt], 0, 0, 0);
      }
    }
    if (kk < 4) {
      *(short8*)&S->As[g][nxt][ar*72 + aseg] = a_n;
      *(short8*)&S->Bs[g][nxt][br*72 + bseg] = b_n0;
      *(short8*)&S->Bs[g][nxt][br*72 + bseg + 8] = b_n1;
    }
    __syncthreads();
  }
  if (g) {
    #pragma unroll
    for (int mt = 0; mt < 2; ++mt)
      *(f32x4*)&S->red[(t*2 + mt)*4] = acc[mt];
  }
  __syncthreads();
  if (!g) {
    #pragma unroll
    for (int mt = 0; mt < 2; ++mt)
      acc[mt] += *(const f32x4*)&S->red[(t*2 + mt)*4];
    int j = n0 + wv*16 + col;
    if (MODE == 0) {
      #pragma unroll
      for (int mt = 0; mt < 2; ++mt)
        #pragma unroll
        for (int r = 0; r < 4; ++r) {
          int row = m0 + mt*16 + quad*4 + r;
          outb[(size_t)row*WCOL + j] = (j < HD) ? f2b(acc[mt][r]) : (short)0;
        }
    } else if (MODE == 1) {
      float bj = (j < HD) ? bias[j] : 0.0f;
      #pragma unroll
      for (int mt = 0; mt < 2; ++mt)
        #pragma unroll
        for (int r = 0; r < 4; ++r) {
          int row = m0 + mt*16 + quad*4 + r;
          outb[(size_t)row*WCOL + j] = (j < HD) ? f2b(ssp_fast(acc[mt][r] + bj)) : (short)0;
        }
    } else {
      #pragma unroll
      for (int mt = 0; mt < 2; ++mt)
        #pragma unroll
        for (int r = 0; r < 4; ++r) {
          int row = m0 + mt*16 + quad*4 + r;
          if (j < HD) {
            float nv = hacc[(size_t)row*HD + j] + acc[mt][r] + bias[j];
            hacc[(size_t)row*HD + j] = nv;
            outb[(size_t)row*WCOL + j] = f2b(nv);
          } else {
            outb[(size_t)row*WCOL + j] = 0;
          }
        }
    }
  }
}

// ---------------- gather phase (coop): 640 groups of 256, 2 iterations ----------------
__device__ __forceinline__ void gather_phase(const short* __restrict__ tabb,
    const float* __restrict__ cval, const int* __restrict__ nbr,
    const float* __restrict__ dist, const short* __restrict__ x1b,
    short* __restrict__ msgb, char* smem_raw) {
  GatherSmem* S = (GatherSmem*)smem_raw;
  int tid = threadIdx.x;
  int grp = tid >> 8, t = tid & 255;
  for (int it = 0; it < 2; ++it) {
    int node = blockIdx.x*2 + grp + it*640;
    bool act = node < NN;
    if (act && t < 64) {
      int e = node*KNB + t;
      S->cvs[grp][t] = cval[e];
      S->nbs[grp][t] = nbr[e];
      float u = dist[e] * ((float)(NKNOT-1)/10.0f);
      int i = (int)u;
      if (i > NKNOT-2) i = NKNOT-2;
      S->tix[grp][t] = i;
      S->tfr[grp][t] = u - (float)i;
    }
    __syncthreads();
    int j = t*4;
    if (act && j < WCOL) {
      if (j >= HD) {
        *(uint2*)&msgb[(size_t)node*WCOL + j] = make_uint2(0u, 0u);
      } else {
        float s[4] = {0.f, 0.f, 0.f, 0.f};
        #pragma unroll 4
        for (int e = 0; e < KNB; ++e) {
          float Ce = S->cvs[grp][e];
          if (Ce == 0.0f) continue;
          const short* w0 = tabb + (size_t)S->tix[grp][e]*HD + j;
          float f = S->tfr[grp][e];
          uint2 wa = *(const uint2*)w0;
          uint2 wb = *(const uint2*)(w0 + HD);
          uint2 xv = *(const uint2*)(x1b + (size_t)S->nbs[grp][e]*WCOL + j);
          float a0 = b2f(wa.x & 0xffffu), a1 = b2f(wa.x >> 16);
          float a2 = b2f(wa.y & 0xffffu), a3 = b2f(wa.y >> 16);
          float b0 = b2f(wb.x & 0xffffu), b1 = b2f(wb.x >> 16);
          float b2v = b2f(wb.y & 0xffffu), b3 = b2f(wb.y >> 16);
          float x0 = b2f(xv.x & 0xffffu), x1v = b2f(xv.x >> 16);
          float x2 = b2f(xv.y & 0xffffu), x3 = b2f(xv.y >> 16);
          s[0] += Ce * (a0 + f*(b0 - a0)) * x0;
          s[1] += Ce * (a1 + f*(b1 - a1)) * x1v;
          s[2] += Ce * (a2 + f*(b2v - a2)) * x2;
          s[3] += Ce * (a3 + f*(b3 - a3)) * x3;
        }
        uint2 pack;
        pack.x = (unsigned)(unsigned short)f2b(s[0]) | ((unsigned)(unsigned short)f2b(s[1]) << 16);
        pack.y = (unsigned)(unsigned short)f2b(s[2]) | ((unsigned)(unsigned short)f2b(s[3]) << 16);
        *(uint2*)&msgb[(size_t)node*WCOL + j] = pack;
      }
    }
    __syncthreads();
  }
}

// ---------------- pool phases (coop) ----------------
__device__ __forceinline__ void pool_mean_phase(const float* __restrict__ h,
    float* __restrict__ pooled, char* smem_raw) {
  PoolSmem* S = (PoolSmem*)smem_raw;
  int bid = blockIdx.x;
  if (bid < 80) {
    int b = bid & 7, cb = bid >> 3;
    int tid = threadIdx.x;
    int cl = tid & 63, q = tid >> 6;
    int c = cb*64 + cl;
    float s = 0.0f;
    if (c < HD) {
      int n0 = q*16;
      #pragma unroll 8
      for (int n = n0; n < n0 + 16; ++n)
        s += h[(size_t)(b*NPG + n)*HD + c];
    }
    S->red[q][cl] = s;
    __syncthreads();
    if (q == 0 && c < HD) {
      float tot = 0.0f;
      #pragma unroll
      for (int qq = 0; qq < 8; ++qq) tot += S->red[qq][cl];
      pooled[(size_t)b*HD + c] = tot * (1.0f/128.0f);
    }
  }
}

__device__ __forceinline__ void pool_out_phase(const float* __restrict__ pooled,
    const float* __restrict__ pw, const float* __restrict__ pb,
    float* __restrict__ out, char* smem_raw) {
  PoolSmem* S = (PoolSmem*)smem_raw;
  int bid = blockIdx.x;
  if (bid < 80) {
    int b = bid / 10, jb = bid - b*10;
    int tid = threadIdx.x;
    int jl = tid & 63, q = tid >> 6;
    int j = jb*64 + jl;
    float s = 0.0f;
    if (j < HD) {
      int c0 = q*75, c1 = c0 + 75;
      for (int c = c0; c < c1; ++c)
        s += pooled[(size_t)b*HD + c] * pw[(size_t)c*HD + j];
    }
    S->red[q][jl] = s;
    __syncthreads();
    if (q == 0 && j < HD) {
      float tot = pb[j];
      #pragma unroll
      for (int qq = 0; qq < 8; ++qq) tot += S->red[qq][jl];
      out[(size_t)b*HD + j] = tot;
    }
  }
}

// ---------------- cooperative layer loop: 320 blocks x 512 threads ----------------
__global__ __launch_bounds__(512, 4) void layers_k(
    const short* __restrict__ nwall, const float* __restrict__ l2b,
    const float* __restrict__ ilb,
    short* __restrict__ h_b, short* __restrict__ x1_b,
    short* __restrict__ msg_b, short* __restrict__ mtmp_b,
    float* __restrict__ h,
    const short* __restrict__ wtab_b, const float* __restrict__ cv,
    const int* __restrict__ nbr, const float* __restrict__ dist,
    float* __restrict__ pooled, const float* __restrict__ pw,
    const float* __restrict__ pb, float* __restrict__ out) {
  __shared__ __align__(16) char smem[sizeof(GemmSmem)];
  cg::grid_group grid = cg::this_grid();
  const size_t WSZ = (size_t)WROW*WCOL;
  int m0 = (blockIdx.x & 31) * 32;
  int n0 = (blockIdx.x >> 5) * 64;
  for (int l = 0; l < LL; ++l) {
    gemm_phase<0>(h_b, nwall + (size_t)(0*6 + l)*WSZ, nullptr, x1_b, nullptr, m0, n0, smem);
    __threadfence(); grid.sync(); __threadfence();
    gather_phase(wtab_b + (size_t)l*NKNOT*HD, cv, nbr, dist, x1_b, msg_b, smem);
    __threadfence(); grid.sync(); __threadfence();
    gemm_phase<1>(msg_b, nwall + (size_t)(1*6 + l)*WSZ, l2b + (size_t)l*HD, mtmp_b, nullptr, m0, n0, smem);
    __threadfence(); grid.sync(); __threadfence();
    gemm_phase<2>(mtmp_b, nwall + (size_t)(2*6 + l)*WSZ, ilb + (size_t)l*HD, h_b, h, m0, n0, smem);
    __threadfence(); grid.sync(); __threadfence();
  }
  pool_mean_phase(h, pooled, smem);
  __threadfence(); grid.sync(); __threadfence();
  pool_out_phase(pooled, pw, pb, out, smem);
}

// ======== fallback (non-coop) kernels — identical math, 2-D grid mapping ========
template<int MODE>
__global__ __launch_bounds__(512) void gemm_node_k(
    const short* __restrict__ A, const short* __restrict__ Bw,
    const float* __restrict__ bias,
    short* __restrict__ outb, float* __restrict__ hacc) {
  __shared__ __align__(16) char smem[sizeof(GemmSmem)];
  gemm_phase<MODE>(A, Bw, bias, outb, hacc, blockIdx.x * 32, blockIdx.y * 64, smem);
}

__global__ __launch_bounds__(192) void gather_k(const short* __restrict__ tabb,
    const float* __restrict__ cval, const int* __restrict__ nbr,
    const float* __restrict__ dist, const short* __restrict__ x1b,
    short* __restrict__ msgb) {
  __shared__ float cvs[64];
  __shared__ int nbs[64];
  __shared__ int tix[64];
  __shared__ float tfr[64];
  int node = blockIdx.x, tid = threadIdx.x;
  if (tid < 64) {
    int e = node*KNB + tid;
    cvs[tid] = cval[e];
    nbs[tid] = nbr[e];
    float u = dist[e] * ((float)(NKNOT-1)/10.0f);
    int i = (int)u;
    if (i > NKNOT-2) i = NKNOT-2;
    tix[tid] = i;
    tfr[tid] = u - (float)i;
  }
  __syncthreads();
  int j = tid*4;
  if (j >= WCOL) return;
  if (j >= HD) {
    *(uint2*)&msgb[(size_t)node*WCOL + j] = make_uint2(0u, 0u);
    return;
  }
  float s[4] = {0.f, 0.f, 0.f, 0.f};
  #pragma unroll 4
  for (int e = 0; e < KNB; ++e) {
    float Ce = cvs[e];
    if (Ce == 0.0f) continue;
    const short* w0 = tabb + (size_t)tix[e]*HD + j;
    float f = tfr[e];
    uint2 wa = *(const uint2*)w0;
    uint2 wb = *(const uint2*)(w0 + HD);
    uint2 xv = *(const uint2*)(x1b + (size_t)nbs[e]*WCOL + j);
    float a0 = b2f(wa.x & 0xffffu), a1 = b2f(wa.x >> 16);
    float a2 = b2f(wa.y & 0xffffu), a3 = b2f(wa.y >> 16);
    float b0 = b2f(wb.x & 0xffffu), b1 = b2f(wb.x >> 16);
    float b2v = b2f(wb.y & 0xffffu), b3 = b2f(wb.y >> 16);
    float x0 = b2f(xv.x & 0xffffu), x1v = b2f(xv.x >> 16);
    float x2 = b2f(xv.y & 0xffffu), x3 = b2f(xv.y >> 16);
    s[0] += Ce * (a0 + f*(b0 - a0)) * x0;
    s[1] += Ce * (a1 + f*(b1 - a1)) * x1v;
    s[2] += Ce * (a2 + f*(b2v - a2)) * x2;
    s[3] += Ce * (a3 + f*(b3 - a3)) * x3;
  }
  uint2 pack;
  pack.x = (unsigned)(unsigned short)f2b(s[0]) | ((unsigned)(unsigned short)f2b(s[1]) << 16);
  pack.y = (unsigned)(unsigned short)f2b(s[2]) | ((unsigned)(unsigned short)f2b(s[3]) << 16);
  *(uint2*)&msgb[(size_t)node*WCOL + j] = pack;
}

__global__ __launch_bounds__(256) void pool_mean_k(const float* __restrict__ h,
                                                   float* __restrict__ pooled) {
  __shared__ float red[4][64];
  int b = blockIdx.x;
  int cl = threadIdx.x & 63, q = threadIdx.x >> 6;
  int c = blockIdx.y*64 + cl;
  float s = 0.0f;
  if (c < HD) {
    int n0 = q*32;
    #pragma unroll 8
    for (int n = n0; n < n0 + 32; ++n)
      s += h[(size_t)(b*NPG + n)*HD + c];
  }
  red[q][cl] = s;
  __syncthreads();
  if (q == 0 && c < HD)
    pooled[(size_t)b*HD + c] =
        (red[0][cl] + red[1][cl] + red[2][cl] + red[3][cl]) * (1.0f/128.0f);
}

__global__ __launch_bounds__(256) void pool_out_k(const float* __restrict__ pooled,
    const float* __restrict__ pw, const float* __restrict__ pb,
    float* __restrict__ out) {
  __shared__ float red[4][64];
  int b = blockIdx.y;
  int tid = threadIdx.x;
  int jl = tid & 63, q = tid >> 6;
  int j = blockIdx.x*64 + jl;
  float s = 0.0f;
  if (j < HD) {
    int c0 = q*150, c1 = c0 + 150;
    for (int c = c0; c < c1; ++c)
      s += pooled[(size_t)b*HD + c] * pw[(size_t)c*HD + j];
  }
  red[q][jl] = s;
  __syncthreads();
  if (q == 0 && j < HD)
    out[(size_t)b*HD + j] = red[0][jl] + red[1][jl] + red[2][jl] + red[3][jl] + pb[j];
}

// ---------------- launch ----------------
extern "C" void kernel_launch(void* const* d_in, const int* in_sizes, int n_in,
                              void* d_out, int out_size, void* d_ws, size_t ws_size,
                              hipStream_t stream) {
  const int*   z    = (const int*)d_in[0];
  const float* pos  = (const float*)d_in[1];
  const float* emb  = (const float*)d_in[2];
  const float* w1   = (const float*)d_in[3];
  const float* b1   = (const float*)d_in[4];
  const float* w2   = (const float*)d_in[5];
  const float* b2   = (const float*)d_in[6];
  const float* l1w  = (const float*)d_in[7];
  const float* l2w  = (const float*)d_in[8];
  const float* l2b  = (const float*)d_in[9];
  const float* ilw  = (const float*)d_in[10];
  const float* ilb  = (const float*)d_in[11];
  const float* pw   = (const float*)d_in[12];
  const float* pb   = (const float*)d_in[13];
  float* ws = (float*)d_ws;
  int*   nbr   = (int*)ws;                   // 65536
  float* cv    = ws + 65536;                 // 65536
  float* dist  = ws + 131072;                // 65536
  float* pooled= ws + 196608;                // 8192
  float* h     = ws + 204800;                // 614400
  short* h_b   = (short*)(ws + 819200);      // 327680 f
  short* msg_b = (short*)(ws + 1146880);     // 327680 f
  short* mtmp_b= (short*)(ws + 1474560);     // 327680 f
  short* x1_b  = (short*)(ws + 1802240);     // 327680 f
  short* basis = (short*)(ws + 2129920);     // 32768 f
  short* ttab  = (short*)(ws + 2162688);     // 1966080 f
  short* wtab_b= (short*)(ws + 4128768);     // 1843200 f
  short* w1b   = (short*)(ws + 5971968);     // 122880 f
  short* nwall = (short*)(ws + 6094848);     // 4915200 f
  float* out   = (float*)d_out;

  const size_t WSZ = (size_t)WROW*WCOL;

  prolog_k<<<5152, 256, 0, stream>>>(pos, nbr, dist, cv,
      w1, basis, w1b, l1w, l2w, ilw, w2, nwall, z, emb, h, h_b);
  tabA_k<<<dim3(LL*(NKNOT/128), 5), 256, 0, stream>>>(basis, w1b, b1, ttab);
  tabB_k<<<dim3(LL*(NKNOT/128), 5), 256, 0, stream>>>(ttab, nwall, b2, wtab_b);

  // cooperative layer loop (24 kernels + 2 pools -> 1 launch); fallback otherwise
  int coop_ok = 0;
  {
    int dev = 0;
    hipGetDevice(&dev);
    hipDeviceGetAttribute(&coop_ok, hipDeviceAttributeCooperativeLaunch, dev);
  }
  hipError_t cerr = hipErrorUnknown;
  if (coop_ok) {
    void* kargs[] = {
      (void*)&nwall, (void*)&l2b, (void*)&ilb,
      (void*)&h_b, (void*)&x1_b, (void*)&msg_b, (void*)&mtmp_b, (void*)&h,
      (void*)&wtab_b, (void*)&cv, (void*)&nbr, (void*)&dist,
      (void*)&pooled, (void*)&pw, (void*)&pb, (void*)&out
    };
    cerr = hipLaunchCooperativeKernel((const void*)layers_k,
        dim3(320), dim3(512), kargs, 0, stream);
  }
  if (cerr != hipSuccess) {
    dim3 gn(32, 10);
    for (int l = 0; l < LL; ++l) {
      gemm_node_k<0><<<gn, 512, 0, stream>>>(h_b, nwall + (size_t)(0*6 + l)*WSZ,
          nullptr, x1_b, nullptr);
      gather_k<<<NN, 192, 0, stream>>>(wtab_b + (size_t)l*NKNOT*HD, cv, nbr, dist, x1_b, msg_b);
      gemm_node_k<1><<<gn, 512, 0, stream>>>(msg_b, nwall + (size_t)(1*6 + l)*WSZ,
          l2b + (size_t)l*HD, mtmp_b, nullptr);
      gemm_node_k<2><<<gn, 512, 0, stream>>>(mtmp_b, nwall + (size_t)(2*6 + l)*WSZ,
          ilb + (size_t)l*HD, h_b, h);
    }
    pool_mean_k<<<dim3(NB, 10), 256, 0, stream>>>(h, pooled);
    pool_out_k<<<dim3(10, NB), 256, 0, stream>>>(pooled, pw, pb, out);
  }
}

// Round 8
// 414.835 us; speedup vs baseline: 9.2429x; 9.2429x over previous
//
#include <hip/hip_runtime.h>
#include <cmath>

#define NB   8
#define NPG  128
#define NN   1024
#define KNB  64
#define HD   600
#define GG   50
#define LL   6
#define WROW 640          // padded weight rows (n)
#define WCOL 640          // padded weight cols (k) — 640 for clean BK=64 split-K
#define NKNOT 1024        // W(d) table knots over [0,10]

typedef __attribute__((ext_vector_type(8))) short short8;
typedef __attribute__((ext_vector_type(4))) short short4v;
typedef __attribute__((ext_vector_type(4))) float f32x4;

__device__ __forceinline__ short f2b(float f) {
  union { float f; unsigned u; } v; v.f = f;
  unsigned u = v.u;
  u += 0x7fffu + ((u >> 16) & 1u);
  return (short)(u >> 16);
}

__device__ __forceinline__ float b2f(unsigned us) {
  union { unsigned u; float f; } v; v.u = us << 16; return v.f;
}

// fast shifted softplus: max(x,0)+log(1+e^-|x|)-ln2
__device__ __forceinline__ float ssp_fast(float x) {
  return fmaxf(x, 0.0f) + __logf(1.0f + __expf(-fabsf(x))) - 0.69314718055994531f;
}

// ---------------- merged prolog: build_graph + prep + conv_all + embed ----------------
__global__ __launch_bounds__(256) void prolog_k(
    const float* __restrict__ pos, int* __restrict__ nbr,
    float* __restrict__ dist, float* __restrict__ cval,
    const float* __restrict__ w1, short* __restrict__ basis, short* __restrict__ w1b,
    const float* __restrict__ l1w, const float* __restrict__ l2w,
    const float* __restrict__ ilw, const float* __restrict__ w2,
    short* __restrict__ nwall,
    const int* __restrict__ z, const float* __restrict__ emb,
    float* __restrict__ h, short* __restrict__ hb) {
  int bid = blockIdx.x;
  int tid = threadIdx.x;
  if (bid < 512) {
#pragma clang fp contract(off)
    __shared__ float d2s[2][128];
    __shared__ int scnt[2];
    int sub = tid >> 7;
    int j = tid & 127;
    int i = bid*2 + sub;
    int li = i & 127;
    int base = i - li;
    if (j == 0) scnt[sub] = 0;
    float px = pos[3*i], py = pos[3*i+1], pz = pos[3*i+2];
    int gj = base + j;
    float dx = px - pos[3*gj], dy = py - pos[3*gj+1], dz = pz - pos[3*gj+2];
    float d2 = dx*dx + dy*dy + dz*dz;
    bool valid = (j != li) && (d2 <= 100.0f);
    d2s[sub][j] = valid ? d2 : 3.0e38f;
    __syncthreads();
    if (valid) {
      atomicAdd(&scnt[sub], 1);
      int rank = 0;
      for (int j2 = 0; j2 < 128; ++j2) {
        float o = d2s[sub][j2];
        rank += (o < d2 || (o == d2 && j2 < j)) ? 1 : 0;
      }
      if (rank < KNB) {
        int e = i*KNB + rank;
        nbr[e] = gj;
        float d = sqrtf(d2);
        dist[e] = d;
        cval[e] = 0.5f * (cosf(d * 0.31415926535897931f) + 1.0f);
      }
    }
    __syncthreads();
    int cnt = scnt[sub]; if (cnt > KNB) cnt = KNB;
    if (j < KNB && j >= cnt) {
      int e = i*KNB + j;
      nbr[e] = i; dist[e] = 0.0f; cval[e] = 0.0f;
    }
  } else if (bid < 1728) {
    int idx = (bid - 512)*256 + tid;
    if (idx < NKNOT*64) {
      int i = idx >> 6, g = idx & 63;
      float v = 0.0f;
      if (g < GG) {
        const float step = 10.0f/49.0f;
        const float coeff = -0.5f/(step*step);
        float d = (float)i * (10.0f/(float)(NKNOT-1));
        float dd = d - step*(float)g;
        v = __expf(coeff*dd*dd);
      }
      basis[idx] = f2b(v);
    } else {
      int r = idx - NKNOT*64;
      if (r < LL*WROW*64) {
        int l = r / (WROW*64); int rem = r - l*WROW*64;
        int n = rem >> 6, k = rem & 63;
        float v = (n < HD && k < GG) ? w1[(size_t)l*GG*HD + (size_t)k*HD + n] : 0.0f;
        w1b[r] = f2b(v);
      }
    }
  } else if (bid < 4128) {
    __shared__ float T[64][65];
    int r = bid - 1728;
    int w = r / 100; int rem = r - w*100;
    int ny = rem / 10, nz = rem - ny*10;
    int kind = w / 6, l = w - kind*6;
    const float* s = (kind == 0) ? l1w : (kind == 1) ? l2w : (kind == 2) ? ilw : w2;
    s += (size_t)l*360000;
    int n0 = ny*64, k0 = nz*64;
    int ta = tid & 63, tb = tid >> 6;
    #pragma unroll
    for (int p = 0; p < 16; ++p) {
      int k = k0 + p*4 + tb;
      int n = n0 + ta;
      T[p*4 + tb][ta] = (k < HD && n < HD) ? s[(size_t)k*HD + n] : 0.0f;
    }
    __syncthreads();
    #pragma unroll
    for (int p = 0; p < 16; ++p) {
      int n = n0 + p*4 + tb;
      int k = k0 + ta;
      if (k < WCOL)
        nwall[(size_t)w*WROW*WCOL + (size_t)n*WCOL + k] = f2b(T[ta][p*4 + tb]);
    }
  } else {
    int i = bid - 4128;
    int zi = z[i];
    for (int j = tid; j < WCOL; j += 256) {
      float v = (j < HD) ? emb[(size_t)zi*HD + j] : 0.0f;
      if (j < HD) h[(size_t)i*HD + j] = v;
      hb[(size_t)i*WCOL + j] = f2b(v);
    }
  }
}

// ---------------- tabA: ttab_all[l] = bf16(ssp(basis@w1[l]+b1[l])) ----------------
__global__ __launch_bounds__(256) void tabA_k(const short* __restrict__ basis,
    const short* __restrict__ w1b, const float* __restrict__ b1all,
    short* __restrict__ ttab_all) {
  const int MT = NKNOT/128;
  int l = blockIdx.x / MT;
  int mb = blockIdx.x - l*MT;
  const short* Bw = w1b + (size_t)l*WROW*64;
  short* outb = ttab_all + (size_t)l*NKNOT*WCOL;
  __shared__ __align__(16) short As[128*40];
  __shared__ __align__(16) short Bs[128*40];
  int tid = threadIdx.x;
  int lane = tid & 63, wv = tid >> 6;
  int wr = wv >> 1, wc = wv & 1;
  int col = lane & 15, quad = lane >> 4;
  int m0 = mb * 128;
  int n0 = blockIdx.y * 128;
  f32x4 acc[4][4] = {};
  for (int k0 = 0; k0 < 64; k0 += 32) {
    #pragma unroll
    for (int rep = 0; rep < 2; ++rep) {
      int s = tid + rep*256;
      int row = s >> 2, seg = s & 3;
      *(short8*)&As[row*40 + seg*8] =
          *(const short8*)(basis + (size_t)(m0 + row)*64 + k0 + seg*8);
      *(short8*)&Bs[row*40 + seg*8] =
          *(const short8*)(Bw + (size_t)(n0 + row)*64 + k0 + seg*8);
    }
    __syncthreads();
    short8 af[4], bf[4];
    #pragma unroll
    for (int mt = 0; mt < 4; ++mt)
      af[mt] = *(const short8*)&As[(wr*64 + mt*16 + col)*40 + quad*8];
    #pragma unroll
    for (int jt = 0; jt < 4; ++jt)
      bf[jt] = *(const short8*)&Bs[(wc*64 + jt*16 + col)*40 + quad*8];
    #pragma unroll
    for (int mt = 0; mt < 4; ++mt)
      #pragma unroll
      for (int jt = 0; jt < 4; ++jt)
        acc[mt][jt] = __builtin_amdgcn_mfma_f32_16x16x32_bf16(af[mt], bf[jt], acc[mt][jt], 0, 0, 0);
    __syncthreads();
  }
  #pragma unroll
  for (int jt = 0; jt < 4; ++jt) {
    int j = n0 + wc*64 + jt*16 + col;
    if (j >= WCOL) continue;
    float bj = (j < HD) ? b1all[(size_t)l*HD + j] : 0.0f;
    #pragma unroll
    for (int mt = 0; mt < 4; ++mt)
      #pragma unroll
      for (int r = 0; r < 4; ++r) {
        int row = m0 + wr*64 + mt*16 + quad*4 + r;
        short v = (j < HD) ? f2b(ssp_fast(acc[mt][jt][r] + bj)) : (short)0;
        outb[(size_t)row*WCOL + j] = v;
      }
  }
}

// ---------------- tabB: wtab_b[l] = bf16(ttab_all[l]@w2[l] + b2[l]); 128x128 tiles ----------------
__global__ __launch_bounds__(256) void tabB_k(const short* __restrict__ ttab_all,
    const short* __restrict__ nwall, const float* __restrict__ b2all,
    short* __restrict__ wtab_b) {
  const int MT = NKNOT/128;
  int l = blockIdx.x / MT;
  int mb = blockIdx.x - l*MT;
  const short* A  = ttab_all + (size_t)l*NKNOT*WCOL;
  const short* Bw = nwall + (size_t)(18 + l)*WROW*WCOL;   // kind=3 (w2)
  short* P = wtab_b + (size_t)l*NKNOT*HD;
  __shared__ __align__(16) short As[128*40];
  __shared__ __align__(16) short Bs[128*40];
  int tid = threadIdx.x;
  int lane = tid & 63, wv = tid >> 6;
  int wr = wv >> 1, wc = wv & 1;
  int col = lane & 15, quad = lane >> 4;
  int m0 = mb * 128;
  int n0 = blockIdx.y * 128;
  f32x4 acc[4][4] = {};
  for (int k0 = 0; k0 < WCOL; k0 += 32) {
    #pragma unroll
    for (int rep = 0; rep < 2; ++rep) {
      int s = tid + rep*256;
      int row = s >> 2, seg = s & 3;
      *(short8*)&As[row*40 + seg*8] =
          *(const short8*)(A + (size_t)(m0 + row)*WCOL + k0 + seg*8);
      *(short8*)&Bs[row*40 + seg*8] =
          *(const short8*)(Bw + (size_t)(n0 + row)*WCOL + k0 + seg*8);
    }
    __syncthreads();
    short8 af[4], bf[4];
    #pragma unroll
    for (int mt = 0; mt < 4; ++mt)
      af[mt] = *(const short8*)&As[(wr*64 + mt*16 + col)*40 + quad*8];
    #pragma unroll
    for (int jt = 0; jt < 4; ++jt)
      bf[jt] = *(const short8*)&Bs[(wc*64 + jt*16 + col)*40 + quad*8];
    #pragma unroll
    for (int mt = 0; mt < 4; ++mt)
      #pragma unroll
      for (int jt = 0; jt < 4; ++jt)
        acc[mt][jt] = __builtin_amdgcn_mfma_f32_16x16x32_bf16(af[mt], bf[jt], acc[mt][jt], 0, 0, 0);
    __syncthreads();
  }
  #pragma unroll
  for (int jt = 0; jt < 4; ++jt) {
    int j = n0 + wc*64 + jt*16 + col;
    if (j >= HD) continue;
    float bj = b2all[(size_t)l*HD + j];
    #pragma unroll
    for (int mt = 0; mt < 4; ++mt)
      #pragma unroll
      for (int r = 0; r < 4; ++r) {
        int row = m0 + wr*64 + mt*16 + quad*4 + r;
        P[(size_t)row*HD + j] = f2b(acc[mt][jt][r] + bj);
      }
  }
}

// ---------------- gather: msg_b[node] = bf16(sum_e C_e * Wtab(d_e) (.) x1[nbr_e]) ----------------
// wtab_b bf16 [NKNOT][600]; x1_b bf16 [NN][640]; 8B (4-col) loads, 192 thr (160 active)
__global__ __launch_bounds__(192) void gather_k(const short* __restrict__ tabb,
    const float* __restrict__ cval, const int* __restrict__ nbr,
    const float* __restrict__ dist, const short* __restrict__ x1b,
    short* __restrict__ msgb) {
  __shared__ float cvs[64];
  __shared__ int nbs[64];
  __shared__ int tix[64];
  __shared__ float tfr[64];
  int node = blockIdx.x, tid = threadIdx.x;
  if (tid < 64) {
    int e = node*KNB + tid;
    cvs[tid] = cval[e];
    nbs[tid] = nbr[e];
    float u = dist[e] * ((float)(NKNOT-1)/10.0f);
    int i = (int)u;
    if (i > NKNOT-2) i = NKNOT-2;
    tix[tid] = i;
    tfr[tid] = u - (float)i;
  }
  __syncthreads();
  int j = tid*4;
  if (j >= WCOL) return;
  if (j >= HD) {                   // j = 600..636: zero the bf16 pads (8B each)
    *(uint2*)&msgb[(size_t)node*WCOL + j] = make_uint2(0u, 0u);
    return;
  }
  float s[4] = {0.f, 0.f, 0.f, 0.f};
  #pragma unroll 4
  for (int e = 0; e < KNB; ++e) {
    float Ce = cvs[e];
    if (Ce == 0.0f) continue;
    const short* w0 = tabb + (size_t)tix[e]*HD + j;
    float f = tfr[e];
    uint2 wa = *(const uint2*)w0;
    uint2 wb = *(const uint2*)(w0 + HD);
    uint2 xv = *(const uint2*)(x1b + (size_t)nbs[e]*WCOL + j);
    float a0 = b2f(wa.x & 0xffffu), a1 = b2f(wa.x >> 16);
    float a2 = b2f(wa.y & 0xffffu), a3 = b2f(wa.y >> 16);
    float b0 = b2f(wb.x & 0xffffu), b1 = b2f(wb.x >> 16);
    float b2v = b2f(wb.y & 0xffffu), b3 = b2f(wb.y >> 16);
    float x0 = b2f(xv.x & 0xffffu), x1v = b2f(xv.x >> 16);
    float x2 = b2f(xv.y & 0xffffu), x3 = b2f(xv.y >> 16);
    s[0] += Ce * (a0 + f*(b0 - a0)) * x0;
    s[1] += Ce * (a1 + f*(b1 - a1)) * x1v;
    s[2] += Ce * (a2 + f*(b2v - a2)) * x2;
    s[3] += Ce * (a3 + f*(b3 - a3)) * x3;
  }
  uint2 pack;
  pack.x = (unsigned)(unsigned short)f2b(s[0]) | ((unsigned)(unsigned short)f2b(s[1]) << 16);
  pack.y = (unsigned)(unsigned short)f2b(s[2]) | ((unsigned)(unsigned short)f2b(s[3]) << 16);
  *(uint2*)&msgb[(size_t)node*WCOL + j] = pack;
}

// ---------------- fused node GEMM: 32x64 tile, 8 waves, 2-way split-K, BK=64 ----------------
// grid (32, 10), 512 threads. Group g handles K half [g*320, g*320+320) as 5 steps of 64,
// double-buffered LDS per group; serial chain = 5 barrier-steps.
// Group 1 dumps its partial acc to LDS; group 0 reduces and runs the epilogue.
// MODE 0: outb = bf16(acc), pads zero               (x1 -> x1_b)
// MODE 1: outb = bf16(ssp(acc+bias)), pads zero     (lin2 -> mtmp_b)
// MODE 2: hacc += acc+bias; outb = bf16(hacc')      (int_lin residual -> h, h_b)
template<int MODE>
__global__ __launch_bounds__(512) void gemm_node_k(
    const short* __restrict__ A, const short* __restrict__ Bw,
    const float* __restrict__ bias,
    short* __restrict__ outb, float* __restrict__ hacc) {
  __shared__ __align__(16) short As[2][2][32*72];   // [group][buf][row*72 + k]
  __shared__ __align__(16) short Bs[2][2][64*72];
  __shared__ __align__(16) float red[256*8];
  int tid = threadIdx.x;
  int g = tid >> 8;                 // K-split group (0 or 1)
  int t = tid & 255;
  int lane = t & 63, wv = t >> 6;
  int col = lane & 15, quad = lane >> 4;
  int m0 = blockIdx.x * 32;         // 2-D grid mapping (fixed in R6 post-mortem)
  int n0 = blockIdx.y * 64;
  int ar = t >> 3, aseg = (t & 7)*8;   // A: 32 rows x 8 segs of 8 shorts
  int br = t >> 2, bseg = (t & 3)*16;  // B: 64 rows x 4 segs of 16 shorts (2x short8)
  const int kb = g * 320;
  const short* Aptr = A  + (size_t)(m0 + ar)*WCOL + kb + aseg;
  const short* Bptr = Bw + (size_t)(n0 + br)*WCOL + kb + bseg;
  f32x4 acc[2] = {};
  {
    short8 a0 = *(const short8*)Aptr;
    short8 b0 = *(const short8*)Bptr;
    short8 b1 = *(const short8*)(Bptr + 8);
    *(short8*)&As[g][0][ar*72 + aseg] = a0;
    *(short8*)&Bs[g][0][br*72 + bseg] = b0;
    *(short8*)&Bs[g][0][br*72 + bseg + 8] = b1;
  }
  __syncthreads();
  for (int kk = 0; kk < 5; ++kk) {
    int cur = kk & 1, nxt = cur ^ 1;
    short8 a_n, b_n0, b_n1;
    if (kk < 4) {
      a_n  = *(const short8*)(Aptr + (kk + 1)*64);
      b_n0 = *(const short8*)(Bptr + (kk + 1)*64);
      b_n1 = *(const short8*)(Bptr + (kk + 1)*64 + 8);
    }
    #pragma unroll
    for (int kh = 0; kh < 2; ++kh) {
      short8 bf = *(const short8*)&Bs[g][cur][(wv*16 + col)*72 + kh*32 + quad*8];
      #pragma unroll
      for (int mt = 0; mt < 2; ++mt) {
        short8 af = *(const short8*)&As[g][cur][(mt*16 + col)*72 + kh*32 + quad*8];
        acc[mt] = __builtin_amdgcn_mfma_f32_16x16x32_bf16(af, bf, acc[mt], 0, 0, 0);
      }
    }
    if (kk < 4) {
      *(short8*)&As[g][nxt][ar*72 + aseg] = a_n;
      *(short8*)&Bs[g][nxt][br*72 + bseg] = b_n0;
      *(short8*)&Bs[g][nxt][br*72 + bseg + 8] = b_n1;
    }
    __syncthreads();
  }
  // cross-group reduction: group 1 -> LDS, group 0 adds
  if (g) {
    #pragma unroll
    for (int mt = 0; mt < 2; ++mt)
      *(f32x4*)&red[(t*2 + mt)*4] = acc[mt];
  }
  __syncthreads();
  if (g) return;
  #pragma unroll
  for (int mt = 0; mt < 2; ++mt)
    acc[mt] += *(const f32x4*)&red[(t*2 + mt)*4];
  int j = n0 + wv*16 + col;
  if (MODE == 0) {
    #pragma unroll
    for (int mt = 0; mt < 2; ++mt)
      #pragma unroll
      for (int r = 0; r < 4; ++r) {
        int row = m0 + mt*16 + quad*4 + r;
        outb[(size_t)row*WCOL + j] = (j < HD) ? f2b(acc[mt][r]) : (short)0;
      }
  } else if (MODE == 1) {
    float bj = (j < HD) ? bias[j] : 0.0f;
    #pragma unroll
    for (int mt = 0; mt < 2; ++mt)
      #pragma unroll
      for (int r = 0; r < 4; ++r) {
        int row = m0 + mt*16 + quad*4 + r;
        outb[(size_t)row*WCOL + j] = (j < HD) ? f2b(ssp_fast(acc[mt][r] + bj)) : (short)0;
      }
  } else {
    #pragma unroll
    for (int mt = 0; mt < 2; ++mt)
      #pragma unroll
      for (int r = 0; r < 4; ++r) {
        int row = m0 + mt*16 + quad*4 + r;
        if (j < HD) {
          float nv = hacc[(size_t)row*HD + j] + acc[mt][r] + bias[j];
          hacc[(size_t)row*HD + j] = nv;
          outb[(size_t)row*WCOL + j] = f2b(nv);
        } else {
          outb[(size_t)row*WCOL + j] = 0;
        }
      }
  }
}

// ---------------- pooling: grid (8, 10); 4-way n-split x 64 cols ----------------
__global__ __launch_bounds__(256) void pool_mean_k(const float* __restrict__ h,
                                                   float* __restrict__ pooled) {
  __shared__ float red[4][64];
  int b = blockIdx.x;
  int cl = threadIdx.x & 63, q = threadIdx.x >> 6;
  int c = blockIdx.y*64 + cl;
  float s = 0.0f;
  if (c < HD) {
    int n0 = q*32;
    #pragma unroll 8
    for (int n = n0; n < n0 + 32; ++n)
      s += h[(size_t)(b*NPG + n)*HD + c];
  }
  red[q][cl] = s;
  __syncthreads();
  if (q == 0 && c < HD)
    pooled[(size_t)b*HD + c] =
        (red[0][cl] + red[1][cl] + red[2][cl] + red[3][cl]) * (1.0f/128.0f);
}

// grid (10, 8): 64 j per block, 4-way c-split, LDS reduce
__global__ __launch_bounds__(256) void pool_out_k(const float* __restrict__ pooled,
    const float* __restrict__ pw, const float* __restrict__ pb,
    float* __restrict__ out) {
  __shared__ float red[4][64];
  int b = blockIdx.y;
  int tid = threadIdx.x;
  int jl = tid & 63, q = tid >> 6;
  int j = blockIdx.x*64 + jl;
  float s = 0.0f;
  if (j < HD) {
    int c0 = q*150, c1 = c0 + 150;
    for (int c = c0; c < c1; ++c)
      s += pooled[(size_t)b*HD + c] * pw[(size_t)c*HD + j];
  }
  red[q][jl] = s;
  __syncthreads();
  if (q == 0 && j < HD)
    out[(size_t)b*HD + j] = red[0][jl] + red[1][jl] + red[2][jl] + red[3][jl] + pb[j];
}

// ---------------- launch ----------------
extern "C" void kernel_launch(void* const* d_in, const int* in_sizes, int n_in,
                              void* d_out, int out_size, void* d_ws, size_t ws_size,
                              hipStream_t stream) {
  const int*   z    = (const int*)d_in[0];
  const float* pos  = (const float*)d_in[1];
  const float* emb  = (const float*)d_in[2];
  const float* w1   = (const float*)d_in[3];
  const float* b1   = (const float*)d_in[4];
  const float* w2   = (const float*)d_in[5];
  const float* b2   = (const float*)d_in[6];
  const float* l1w  = (const float*)d_in[7];
  const float* l2w  = (const float*)d_in[8];
  const float* l2b  = (const float*)d_in[9];
  const float* ilw  = (const float*)d_in[10];
  const float* ilb  = (const float*)d_in[11];
  const float* pw   = (const float*)d_in[12];
  const float* pb   = (const float*)d_in[13];
  float* ws = (float*)d_ws;
  int*   nbr   = (int*)ws;                   // 65536
  float* cv    = ws + 65536;                 // 65536
  float* dist  = ws + 131072;                // 65536
  float* pooled= ws + 196608;                // 8192
  float* h     = ws + 204800;                // 614400
  short* h_b   = (short*)(ws + 819200);      // 1024*640 sh = 327680 f
  short* msg_b = (short*)(ws + 1146880);     // 327680 f
  short* mtmp_b= (short*)(ws + 1474560);     // 327680 f
  short* x1_b  = (short*)(ws + 1802240);     // 327680 f
  short* basis = (short*)(ws + 2129920);     // 32768 f
  short* ttab  = (short*)(ws + 2162688);     // 1966080 f
  short* wtab_b= (short*)(ws + 4128768);     // 1843200 f
  short* w1b   = (short*)(ws + 5971968);     // 122880 f
  short* nwall = (short*)(ws + 6094848);     // 4915200 f
  float* out   = (float*)d_out;

  const size_t WSZ = (size_t)WROW*WCOL;

  prolog_k<<<5152, 256, 0, stream>>>(pos, nbr, dist, cv,
      w1, basis, w1b, l1w, l2w, ilw, w2, nwall, z, emb, h, h_b);
  tabA_k<<<dim3(LL*(NKNOT/128), 5), 256, 0, stream>>>(basis, w1b, b1, ttab);
  tabB_k<<<dim3(LL*(NKNOT/128), 5), 256, 0, stream>>>(ttab, nwall, b2, wtab_b);

  dim3 gn(32, 10);
  for (int l = 0; l < LL; ++l) {
    // x1_b = bf16(h @ lin1_w[l])
    gemm_node_k<0><<<gn, 512, 0, stream>>>(h_b, nwall + (size_t)(0*6 + l)*WSZ,
        nullptr, x1_b, nullptr);
    // msg_b[node] = bf16(sum_e C_e * Wtab(d_e) (.) x1[nbr_e])
    gather_k<<<NN, 192, 0, stream>>>(wtab_b + (size_t)l*NKNOT*HD, cv, nbr, dist, x1_b, msg_b);
    // mtmp_b = bf16(ssp(msg @ lin2_w[l] + lin2_b[l]))
    gemm_node_k<1><<<gn, 512, 0, stream>>>(msg_b, nwall + (size_t)(1*6 + l)*WSZ,
        l2b + (size_t)l*HD, mtmp_b, nullptr);
    // h += mtmp @ int_lin_w[l] + int_lin_b[l]; h_b = bf16(h)
    gemm_node_k<2><<<gn, 512, 0, stream>>>(mtmp_b, nwall + (size_t)(2*6 + l)*WSZ,
        ilb + (size_t)l*HD, h_b, h);
  }
  pool_mean_k<<<dim3(NB, 10), 256, 0, stream>>>(h, pooled);
  pool_out_k<<<dim3(10, NB), 256, 0, stream>>>(pooled, pw, pb, out);
}

// Round 9
// 413.694 us; speedup vs baseline: 9.2684x; 1.0028x over previous
//
#include <hip/hip_runtime.h>
#include <cmath>

#define NB   8
#define NPG  128
#define NN   1024
#define KNB  64
#define HD   600
#define GG   50
#define LL   6
#define WROW 640          // padded weight rows (n)
#define WCOL 640          // padded weight cols (k) — 640 for clean BK=64 split-K
#define NKNOT 1024        // W(d) table knots over [0,10]

typedef __attribute__((ext_vector_type(8))) short short8;
typedef __attribute__((ext_vector_type(4))) short short4v;
typedef __attribute__((ext_vector_type(4))) float f32x4;

__device__ __forceinline__ short f2b(float f) {
  union { float f; unsigned u; } v; v.f = f;
  unsigned u = v.u;
  u += 0x7fffu + ((u >> 16) & 1u);
  return (short)(u >> 16);
}

__device__ __forceinline__ float b2f(unsigned us) {
  union { unsigned u; float f; } v; v.u = us << 16; return v.f;
}

// fast shifted softplus: max(x,0)+log(1+e^-|x|)-ln2
__device__ __forceinline__ float ssp_fast(float x) {
  return fmaxf(x, 0.0f) + __logf(1.0f + __expf(-fabsf(x))) - 0.69314718055994531f;
}

// ---------------- merged prolog: build_graph + prep + conv_all + embed ----------------
__global__ __launch_bounds__(256) void prolog_k(
    const float* __restrict__ pos, int* __restrict__ nbr,
    float* __restrict__ dist, float* __restrict__ cval,
    const float* __restrict__ w1, short* __restrict__ basis, short* __restrict__ w1b,
    const float* __restrict__ l1w, const float* __restrict__ l2w,
    const float* __restrict__ ilw, const float* __restrict__ w2,
    short* __restrict__ nwall,
    const int* __restrict__ z, const float* __restrict__ emb,
    float* __restrict__ h, short* __restrict__ hb) {
  int bid = blockIdx.x;
  int tid = threadIdx.x;
  if (bid < 512) {
#pragma clang fp contract(off)
    __shared__ float d2s[2][128];
    __shared__ int scnt[2];
    int sub = tid >> 7;
    int j = tid & 127;
    int i = bid*2 + sub;
    int li = i & 127;
    int base = i - li;
    if (j == 0) scnt[sub] = 0;
    float px = pos[3*i], py = pos[3*i+1], pz = pos[3*i+2];
    int gj = base + j;
    float dx = px - pos[3*gj], dy = py - pos[3*gj+1], dz = pz - pos[3*gj+2];
    float d2 = dx*dx + dy*dy + dz*dz;
    bool valid = (j != li) && (d2 <= 100.0f);
    d2s[sub][j] = valid ? d2 : 3.0e38f;
    __syncthreads();
    if (valid) {
      atomicAdd(&scnt[sub], 1);
      int rank = 0;
      for (int j2 = 0; j2 < 128; ++j2) {
        float o = d2s[sub][j2];
        rank += (o < d2 || (o == d2 && j2 < j)) ? 1 : 0;
      }
      if (rank < KNB) {
        int e = i*KNB + rank;
        nbr[e] = gj;
        float d = sqrtf(d2);
        dist[e] = d;
        cval[e] = 0.5f * (cosf(d * 0.31415926535897931f) + 1.0f);
      }
    }
    __syncthreads();
    int cnt = scnt[sub]; if (cnt > KNB) cnt = KNB;
    if (j < KNB && j >= cnt) {
      int e = i*KNB + j;
      nbr[e] = i; dist[e] = 0.0f; cval[e] = 0.0f;
    }
  } else if (bid < 1728) {
    int idx = (bid - 512)*256 + tid;
    if (idx < NKNOT*64) {
      int i = idx >> 6, g = idx & 63;
      float v = 0.0f;
      if (g < GG) {
        const float step = 10.0f/49.0f;
        const float coeff = -0.5f/(step*step);
        float d = (float)i * (10.0f/(float)(NKNOT-1));
        float dd = d - step*(float)g;
        v = __expf(coeff*dd*dd);
      }
      basis[idx] = f2b(v);
    } else {
      int r = idx - NKNOT*64;
      if (r < LL*WROW*64) {
        int l = r / (WROW*64); int rem = r - l*WROW*64;
        int n = rem >> 6, k = rem & 63;
        float v = (n < HD && k < GG) ? w1[(size_t)l*GG*HD + (size_t)k*HD + n] : 0.0f;
        w1b[r] = f2b(v);
      }
    }
  } else if (bid < 4128) {
    __shared__ float T[64][65];
    int r = bid - 1728;
    int w = r / 100; int rem = r - w*100;
    int ny = rem / 10, nz = rem - ny*10;
    int kind = w / 6, l = w - kind*6;
    const float* s = (kind == 0) ? l1w : (kind == 1) ? l2w : (kind == 2) ? ilw : w2;
    s += (size_t)l*360000;
    int n0 = ny*64, k0 = nz*64;
    int ta = tid & 63, tb = tid >> 6;
    #pragma unroll
    for (int p = 0; p < 16; ++p) {
      int k = k0 + p*4 + tb;
      int n = n0 + ta;
      T[p*4 + tb][ta] = (k < HD && n < HD) ? s[(size_t)k*HD + n] : 0.0f;
    }
    __syncthreads();
    #pragma unroll
    for (int p = 0; p < 16; ++p) {
      int n = n0 + p*4 + tb;
      int k = k0 + ta;
      if (k < WCOL)
        nwall[(size_t)w*WROW*WCOL + (size_t)n*WCOL + k] = f2b(T[ta][p*4 + tb]);
    }
  } else {
    int i = bid - 4128;
    int zi = z[i];
    for (int j = tid; j < WCOL; j += 256) {
      float v = (j < HD) ? emb[(size_t)zi*HD + j] : 0.0f;
      if (j < HD) h[(size_t)i*HD + j] = v;
      hb[(size_t)i*WCOL + j] = f2b(v);
    }
  }
}

// ---------------- tabA: ttab_all[l] = bf16(ssp(basis@w1[l]+b1[l])) ----------------
__global__ __launch_bounds__(256) void tabA_k(const short* __restrict__ basis,
    const short* __restrict__ w1b, const float* __restrict__ b1all,
    short* __restrict__ ttab_all) {
  const int MT = NKNOT/128;
  int l = blockIdx.x / MT;
  int mb = blockIdx.x - l*MT;
  const short* Bw = w1b + (size_t)l*WROW*64;
  short* outb = ttab_all + (size_t)l*NKNOT*WCOL;
  __shared__ __align__(16) short As[128*40];
  __shared__ __align__(16) short Bs[128*40];
  int tid = threadIdx.x;
  int lane = tid & 63, wv = tid >> 6;
  int wr = wv >> 1, wc = wv & 1;
  int col = lane & 15, quad = lane >> 4;
  int m0 = mb * 128;
  int n0 = blockIdx.y * 128;
  f32x4 acc[4][4] = {};
  for (int k0 = 0; k0 < 64; k0 += 32) {
    #pragma unroll
    for (int rep = 0; rep < 2; ++rep) {
      int s = tid + rep*256;
      int row = s >> 2, seg = s & 3;
      *(short8*)&As[row*40 + seg*8] =
          *(const short8*)(basis + (size_t)(m0 + row)*64 + k0 + seg*8);
      *(short8*)&Bs[row*40 + seg*8] =
          *(const short8*)(Bw + (size_t)(n0 + row)*64 + k0 + seg*8);
    }
    __syncthreads();
    short8 af[4], bf[4];
    #pragma unroll
    for (int mt = 0; mt < 4; ++mt)
      af[mt] = *(const short8*)&As[(wr*64 + mt*16 + col)*40 + quad*8];
    #pragma unroll
    for (int jt = 0; jt < 4; ++jt)
      bf[jt] = *(const short8*)&Bs[(wc*64 + jt*16 + col)*40 + quad*8];
    #pragma unroll
    for (int mt = 0; mt < 4; ++mt)
      #pragma unroll
      for (int jt = 0; jt < 4; ++jt)
        acc[mt][jt] = __builtin_amdgcn_mfma_f32_16x16x32_bf16(af[mt], bf[jt], acc[mt][jt], 0, 0, 0);
    __syncthreads();
  }
  #pragma unroll
  for (int jt = 0; jt < 4; ++jt) {
    int j = n0 + wc*64 + jt*16 + col;
    if (j >= WCOL) continue;
    float bj = (j < HD) ? b1all[(size_t)l*HD + j] : 0.0f;
    #pragma unroll
    for (int mt = 0; mt < 4; ++mt)
      #pragma unroll
      for (int r = 0; r < 4; ++r) {
        int row = m0 + wr*64 + mt*16 + quad*4 + r;
        short v = (j < HD) ? f2b(ssp_fast(acc[mt][jt][r] + bj)) : (short)0;
        outb[(size_t)row*WCOL + j] = v;
      }
  }
}

// ---------------- tabB: wtab_b[l] = bf16(ttab_all[l]@w2[l] + b2[l]); 128x128 tiles ----------------
__global__ __launch_bounds__(256) void tabB_k(const short* __restrict__ ttab_all,
    const short* __restrict__ nwall, const float* __restrict__ b2all,
    short* __restrict__ wtab_b) {
  const int MT = NKNOT/128;
  int l = blockIdx.x / MT;
  int mb = blockIdx.x - l*MT;
  const short* A  = ttab_all + (size_t)l*NKNOT*WCOL;
  const short* Bw = nwall + (size_t)(18 + l)*WROW*WCOL;   // kind=3 (w2)
  short* P = wtab_b + (size_t)l*NKNOT*HD;
  __shared__ __align__(16) short As[128*40];
  __shared__ __align__(16) short Bs[128*40];
  int tid = threadIdx.x;
  int lane = tid & 63, wv = tid >> 6;
  int wr = wv >> 1, wc = wv & 1;
  int col = lane & 15, quad = lane >> 4;
  int m0 = mb * 128;
  int n0 = blockIdx.y * 128;
  f32x4 acc[4][4] = {};
  for (int k0 = 0; k0 < WCOL; k0 += 32) {
    #pragma unroll
    for (int rep = 0; rep < 2; ++rep) {
      int s = tid + rep*256;
      int row = s >> 2, seg = s & 3;
      *(short8*)&As[row*40 + seg*8] =
          *(const short8*)(A + (size_t)(m0 + row)*WCOL + k0 + seg*8);
      *(short8*)&Bs[row*40 + seg*8] =
          *(const short8*)(Bw + (size_t)(n0 + row)*WCOL + k0 + seg*8);
    }
    __syncthreads();
    short8 af[4], bf[4];
    #pragma unroll
    for (int mt = 0; mt < 4; ++mt)
      af[mt] = *(const short8*)&As[(wr*64 + mt*16 + col)*40 + quad*8];
    #pragma unroll
    for (int jt = 0; jt < 4; ++jt)
      bf[jt] = *(const short8*)&Bs[(wc*64 + jt*16 + col)*40 + quad*8];
    #pragma unroll
    for (int mt = 0; mt < 4; ++mt)
      #pragma unroll
      for (int jt = 0; jt < 4; ++jt)
        acc[mt][jt] = __builtin_amdgcn_mfma_f32_16x16x32_bf16(af[mt], bf[jt], acc[mt][jt], 0, 0, 0);
    __syncthreads();
  }
  #pragma unroll
  for (int jt = 0; jt < 4; ++jt) {
    int j = n0 + wc*64 + jt*16 + col;
    if (j >= HD) continue;
    float bj = b2all[(size_t)l*HD + j];
    #pragma unroll
    for (int mt = 0; mt < 4; ++mt)
      #pragma unroll
      for (int r = 0; r < 4; ++r) {
        int row = m0 + wr*64 + mt*16 + quad*4 + r;
        P[(size_t)row*HD + j] = f2b(acc[mt][jt][r] + bj);
      }
  }
}

// ---------------- gather: msg_b[node] = bf16(sum_e C_e * Wtab(d_e) (.) x1[nbr_e]) ----------------
// 320 threads x 2 cols (4B loads): 5 waves/block for latency hiding on the L2/L3 edge loop
__global__ __launch_bounds__(320) void gather_k(const short* __restrict__ tabb,
    const float* __restrict__ cval, const int* __restrict__ nbr,
    const float* __restrict__ dist, const short* __restrict__ x1b,
    short* __restrict__ msgb) {
  __shared__ float cvs[64];
  __shared__ int nbs[64];
  __shared__ int tix[64];
  __shared__ float tfr[64];
  int node = blockIdx.x, tid = threadIdx.x;
  if (tid < 64) {
    int e = node*KNB + tid;
    cvs[tid] = cval[e];
    nbs[tid] = nbr[e];
    float u = dist[e] * ((float)(NKNOT-1)/10.0f);
    int i = (int)u;
    if (i > NKNOT-2) i = NKNOT-2;
    tix[tid] = i;
    tfr[tid] = u - (float)i;
  }
  __syncthreads();
  int j = tid*2;                   // j in [0,640)
  if (j >= HD) {                   // j = 600..638: zero the bf16 pads (4B each)
    *(unsigned*)&msgb[(size_t)node*WCOL + j] = 0u;
    return;
  }
  float s0 = 0.f, s1 = 0.f;
  #pragma unroll 4
  for (int e = 0; e < KNB; ++e) {
    float Ce = cvs[e];
    if (Ce == 0.0f) continue;
    const short* w0 = tabb + (size_t)tix[e]*HD + j;
    float f = tfr[e];
    unsigned wa = *(const unsigned*)w0;
    unsigned wb = *(const unsigned*)(w0 + HD);
    unsigned xv = *(const unsigned*)(x1b + (size_t)nbs[e]*WCOL + j);
    float a0 = b2f(wa & 0xffffu), a1 = b2f(wa >> 16);
    float b0 = b2f(wb & 0xffffu), b1 = b2f(wb >> 16);
    float x0 = b2f(xv & 0xffffu), x1v = b2f(xv >> 16);
    s0 += Ce * (a0 + f*(b0 - a0)) * x0;
    s1 += Ce * (a1 + f*(b1 - a1)) * x1v;
  }
  unsigned pack = (unsigned)(unsigned short)f2b(s0) |
                  ((unsigned)(unsigned short)f2b(s1) << 16);
  *(unsigned*)&msgb[(size_t)node*WCOL + j] = pack;
}

// ---------------- fused node GEMM: 32x64 tile, 8 waves, 2-way split-K, BK=64 ----------------
// grid (32, 10), 512 threads. Group g handles K half [g*320, +320) as 5 steps of 64.
// 2-ahead REGISTER prefetch (fully unrolled, static idx) removes the per-step global
// load latency from the barrier chain; ds_writes placed AFTER the MFMAs of the step.
// MODE 0: outb = bf16(acc), pads zero               (x1 -> x1_b)
// MODE 1: outb = bf16(ssp(acc+bias)), pads zero     (lin2 -> mtmp_b)
// MODE 2: hacc += acc+bias; outb = bf16(hacc')      (int_lin residual -> h, h_b)
template<int MODE>
__global__ __launch_bounds__(512) void gemm_node_k(
    const short* __restrict__ A, const short* __restrict__ Bw,
    const float* __restrict__ bias,
    short* __restrict__ outb, float* __restrict__ hacc) {
  __shared__ __align__(16) short As[2][2][32*72];   // [group][buf][row*72 + k]
  __shared__ __align__(16) short Bs[2][2][64*72];
  __shared__ __align__(16) float red[256*8];
  int tid = threadIdx.x;
  int g = tid >> 8;                 // K-split group (0 or 1)
  int t = tid & 255;
  int lane = t & 63, wv = t >> 6;
  int col = lane & 15, quad = lane >> 4;
  int m0 = blockIdx.x * 32;
  int n0 = blockIdx.y * 64;
  int ar = t >> 3, aseg = (t & 7)*8;   // A: 32 rows x 8 segs of 8 shorts
  int br = t >> 2, bseg = (t & 3)*16;  // B: 64 rows x 4 segs of 16 shorts (2x short8)
  const int kb = g * 320;
  const short* Aptr = A  + (size_t)(m0 + ar)*WCOL + kb + aseg;
  const short* Bptr = Bw + (size_t)(n0 + br)*WCOL + kb + bseg;
  short8 a_pre[5], b0_pre[5], b1_pre[5];
  a_pre[0]  = *(const short8*)Aptr;
  b0_pre[0] = *(const short8*)Bptr;
  b1_pre[0] = *(const short8*)(Bptr + 8);
  a_pre[1]  = *(const short8*)(Aptr + 64);
  b0_pre[1] = *(const short8*)(Bptr + 64);
  b1_pre[1] = *(const short8*)(Bptr + 72);
  *(short8*)&As[g][0][ar*72 + aseg] = a_pre[0];
  *(short8*)&Bs[g][0][br*72 + bseg] = b0_pre[0];
  *(short8*)&Bs[g][0][br*72 + bseg + 8] = b1_pre[0];
  __syncthreads();
  f32x4 acc[2] = {};
  #pragma unroll
  for (int kk = 0; kk < 5; ++kk) {
    const int cur = kk & 1, nxt = cur ^ 1;
    if (kk + 2 < 5) {               // issue loads 2 steps ahead (no wait here)
      a_pre[kk+2]  = *(const short8*)(Aptr + (kk+2)*64);
      b0_pre[kk+2] = *(const short8*)(Bptr + (kk+2)*64);
      b1_pre[kk+2] = *(const short8*)(Bptr + (kk+2)*64 + 8);
    }
    #pragma unroll
    for (int kh = 0; kh < 2; ++kh) {
      short8 bf = *(const short8*)&Bs[g][cur][(wv*16 + col)*72 + kh*32 + quad*8];
      #pragma unroll
      for (int mt = 0; mt < 2; ++mt) {
        short8 af = *(const short8*)&As[g][cur][(mt*16 + col)*72 + kh*32 + quad*8];
        acc[mt] = __builtin_amdgcn_mfma_f32_16x16x32_bf16(af, bf, acc[mt], 0, 0, 0);
      }
    }
    if (kk < 4) {                   // stage next step (loaded >=1 iter ago)
      *(short8*)&As[g][nxt][ar*72 + aseg] = a_pre[kk+1];
      *(short8*)&Bs[g][nxt][br*72 + bseg] = b0_pre[kk+1];
      *(short8*)&Bs[g][nxt][br*72 + bseg + 8] = b1_pre[kk+1];
    }
    __syncthreads();
  }
  // cross-group reduction: group 1 -> LDS, group 0 adds
  if (g) {
    #pragma unroll
    for (int mt = 0; mt < 2; ++mt)
      *(f32x4*)&red[(t*2 + mt)*4] = acc[mt];
  }
  __syncthreads();
  if (g) return;
  #pragma unroll
  for (int mt = 0; mt < 2; ++mt)
    acc[mt] += *(const f32x4*)&red[(t*2 + mt)*4];
  int j = n0 + wv*16 + col;
  if (MODE == 0) {
    #pragma unroll
    for (int mt = 0; mt < 2; ++mt)
      #pragma unroll
      for (int r = 0; r < 4; ++r) {
        int row = m0 + mt*16 + quad*4 + r;
        outb[(size_t)row*WCOL + j] = (j < HD) ? f2b(acc[mt][r]) : (short)0;
      }
  } else if (MODE == 1) {
    float bj = (j < HD) ? bias[j] : 0.0f;
    #pragma unroll
    for (int mt = 0; mt < 2; ++mt)
      #pragma unroll
      for (int r = 0; r < 4; ++r) {
        int row = m0 + mt*16 + quad*4 + r;
        outb[(size_t)row*WCOL + j] = (j < HD) ? f2b(ssp_fast(acc[mt][r] + bj)) : (short)0;
      }
  } else {
    #pragma unroll
    for (int mt = 0; mt < 2; ++mt)
      #pragma unroll
      for (int r = 0; r < 4; ++r) {
        int row = m0 + mt*16 + quad*4 + r;
        if (j < HD) {
          float nv = hacc[(size_t)row*HD + j] + acc[mt][r] + bias[j];
          hacc[(size_t)row*HD + j] = nv;
          outb[(size_t)row*WCOL + j] = f2b(nv);
        } else {
          outb[(size_t)row*WCOL + j] = 0;
        }
      }
  }
}

// ---------------- pooling: grid (8, 10); 4-way n-split x 64 cols ----------------
__global__ __launch_bounds__(256) void pool_mean_k(const float* __restrict__ h,
                                                   float* __restrict__ pooled) {
  __shared__ float red[4][64];
  int b = blockIdx.x;
  int cl = threadIdx.x & 63, q = threadIdx.x >> 6;
  int c = blockIdx.y*64 + cl;
  float s = 0.0f;
  if (c < HD) {
    int n0 = q*32;
    #pragma unroll 8
    for (int n = n0; n < n0 + 32; ++n)
      s += h[(size_t)(b*NPG + n)*HD + c];
  }
  red[q][cl] = s;
  __syncthreads();
  if (q == 0 && c < HD)
    pooled[(size_t)b*HD + c] =
        (red[0][cl] + red[1][cl] + red[2][cl] + red[3][cl]) * (1.0f/128.0f);
}

// grid (10, 8): 64 j per block, 4-way c-split, LDS reduce
__global__ __launch_bounds__(256) void pool_out_k(const float* __restrict__ pooled,
    const float* __restrict__ pw, const float* __restrict__ pb,
    float* __restrict__ out) {
  __shared__ float red[4][64];
  int b = blockIdx.y;
  int tid = threadIdx.x;
  int jl = tid & 63, q = tid >> 6;
  int j = blockIdx.x*64 + jl;
  float s = 0.0f;
  if (j < HD) {
    int c0 = q*150, c1 = c0 + 150;
    for (int c = c0; c < c1; ++c)
      s += pooled[(size_t)b*HD + c] * pw[(size_t)c*HD + j];
  }
  red[q][jl] = s;
  __syncthreads();
  if (q == 0 && j < HD)
    out[(size_t)b*HD + j] = red[0][jl] + red[1][jl] + red[2][jl] + red[3][jl] + pb[j];
}

// ---------------- launch ----------------
extern "C" void kernel_launch(void* const* d_in, const int* in_sizes, int n_in,
                              void* d_out, int out_size, void* d_ws, size_t ws_size,
                              hipStream_t stream) {
  const int*   z    = (const int*)d_in[0];
  const float* pos  = (const float*)d_in[1];
  const float* emb  = (const float*)d_in[2];
  const float* w1   = (const float*)d_in[3];
  const float* b1   = (const float*)d_in[4];
  const float* w2   = (const float*)d_in[5];
  const float* b2   = (const float*)d_in[6];
  const float* l1w  = (const float*)d_in[7];
  const float* l2w  = (const float*)d_in[8];
  const float* l2b  = (const float*)d_in[9];
  const float* ilw  = (const float*)d_in[10];
  const float* ilb  = (const float*)d_in[11];
  const float* pw   = (const float*)d_in[12];
  const float* pb   = (const float*)d_in[13];
  float* ws = (float*)d_ws;
  int*   nbr   = (int*)ws;                   // 65536
  float* cv    = ws + 65536;                 // 65536
  float* dist  = ws + 131072;                // 65536
  float* pooled= ws + 196608;                // 8192
  float* h     = ws + 204800;                // 614400
  short* h_b   = (short*)(ws + 819200);      // 1024*640 sh = 327680 f
  short* msg_b = (short*)(ws + 1146880);     // 327680 f
  short* mtmp_b= (short*)(ws + 1474560);     // 327680 f
  short* x1_b  = (short*)(ws + 1802240);     // 327680 f
  short* basis = (short*)(ws + 2129920);     // 32768 f
  short* ttab  = (short*)(ws + 2162688);     // 1966080 f
  short* wtab_b= (short*)(ws + 4128768);     // 1843200 f
  short* w1b   = (short*)(ws + 5971968);     // 122880 f
  short* nwall = (short*)(ws + 6094848);     // 4915200 f
  float* out   = (float*)d_out;

  const size_t WSZ = (size_t)WROW*WCOL;

  prolog_k<<<5152, 256, 0, stream>>>(pos, nbr, dist, cv,
      w1, basis, w1b, l1w, l2w, ilw, w2, nwall, z, emb, h, h_b);
  tabA_k<<<dim3(LL*(NKNOT/128), 5), 256, 0, stream>>>(basis, w1b, b1, ttab);
  tabB_k<<<dim3(LL*(NKNOT/128), 5), 256, 0, stream>>>(ttab, nwall, b2, wtab_b);

  dim3 gn(32, 10);
  for (int l = 0; l < LL; ++l) {
    // x1_b = bf16(h @ lin1_w[l])
    gemm_node_k<0><<<gn, 512, 0, stream>>>(h_b, nwall + (size_t)(0*6 + l)*WSZ,
        nullptr, x1_b, nullptr);
    // msg_b[node] = bf16(sum_e C_e * Wtab(d_e) (.) x1[nbr_e])
    gather_k<<<NN, 320, 0, stream>>>(wtab_b + (size_t)l*NKNOT*HD, cv, nbr, dist, x1_b, msg_b);
    // mtmp_b = bf16(ssp(msg @ lin2_w[l] + lin2_b[l]))
    gemm_node_k<1><<<gn, 512, 0, stream>>>(msg_b, nwall + (size_t)(1*6 + l)*WSZ,
        l2b + (size_t)l*HD, mtmp_b, nullptr);
    // h += mtmp @ int_lin_w[l] + int_lin_b[l]; h_b = bf16(h)
    gemm_node_k<2><<<gn, 512, 0, stream>>>(mtmp_b, nwall + (size_t)(2*6 + l)*WSZ,
        ilb + (size_t)l*HD, h_b, h);
  }
  pool_mean_k<<<dim3(NB, 10), 256, 0, stream>>>(h, pooled);
  pool_out_k<<<dim3(10, NB), 256, 0, stream>>>(pooled, pw, pb, out);
}

// Round 10
// 408.886 us; speedup vs baseline: 9.3774x; 1.0118x over previous
//
#include <hip/hip_runtime.h>
#include <cmath>

#define NB   8
#define NPG  128
#define NN   1024
#define KNB  64
#define HD   600
#define GG   50
#define LL   6
#define WROW 640          // padded weight rows (n)
#define WCOL 640          // padded weight cols (k) — 640 for clean BK=64 split-K
#define NKNOT 1024        // W(d) table knots over [0,10]

typedef __attribute__((ext_vector_type(8))) short short8;
typedef __attribute__((ext_vector_type(4))) float f32x4;

// async global->LDS DMA, 16B per lane (wave-uniform LDS base + lane*16)
#define GLOAD16(gsrc, ldst) \
  __builtin_amdgcn_global_load_lds( \
      (const __attribute__((address_space(1))) void*)(gsrc), \
      (__attribute__((address_space(3))) void*)(ldst), 16, 0, 0)

__device__ __forceinline__ short f2b(float f) {
  union { float f; unsigned u; } v; v.f = f;
  unsigned u = v.u;
  u += 0x7fffu + ((u >> 16) & 1u);
  return (short)(u >> 16);
}

__device__ __forceinline__ float b2f(unsigned us) {
  union { unsigned u; float f; } v; v.u = us << 16; return v.f;
}

// fast shifted softplus: max(x,0)+log(1+e^-|x|)-ln2
__device__ __forceinline__ float ssp_fast(float x) {
  return fmaxf(x, 0.0f) + __logf(1.0f + __expf(-fabsf(x))) - 0.69314718055994531f;
}

// ---------------- merged prolog: build_graph + prep + conv_all + embed ----------------
__global__ __launch_bounds__(256) void prolog_k(
    const float* __restrict__ pos, int* __restrict__ nbr,
    float* __restrict__ dist, float* __restrict__ cval,
    const float* __restrict__ w1, short* __restrict__ basis, short* __restrict__ w1b,
    const float* __restrict__ l1w, const float* __restrict__ l2w,
    const float* __restrict__ ilw, const float* __restrict__ w2,
    short* __restrict__ nwall,
    const int* __restrict__ z, const float* __restrict__ emb,
    float* __restrict__ h, short* __restrict__ hb) {
  int bid = blockIdx.x;
  int tid = threadIdx.x;
  if (bid < 512) {
#pragma clang fp contract(off)
    __shared__ float d2s[2][128];
    __shared__ int scnt[2];
    int sub = tid >> 7;
    int j = tid & 127;
    int i = bid*2 + sub;
    int li = i & 127;
    int base = i - li;
    if (j == 0) scnt[sub] = 0;
    float px = pos[3*i], py = pos[3*i+1], pz = pos[3*i+2];
    int gj = base + j;
    float dx = px - pos[3*gj], dy = py - pos[3*gj+1], dz = pz - pos[3*gj+2];
    float d2 = dx*dx + dy*dy + dz*dz;
    bool valid = (j != li) && (d2 <= 100.0f);
    d2s[sub][j] = valid ? d2 : 3.0e38f;
    __syncthreads();
    if (valid) {
      atomicAdd(&scnt[sub], 1);
      int rank = 0;
      for (int j2 = 0; j2 < 128; ++j2) {
        float o = d2s[sub][j2];
        rank += (o < d2 || (o == d2 && j2 < j)) ? 1 : 0;
      }
      if (rank < KNB) {
        int e = i*KNB + rank;
        nbr[e] = gj;
        float d = sqrtf(d2);
        dist[e] = d;
        cval[e] = 0.5f * (cosf(d * 0.31415926535897931f) + 1.0f);
      }
    }
    __syncthreads();
    int cnt = scnt[sub]; if (cnt > KNB) cnt = KNB;
    if (j < KNB && j >= cnt) {
      int e = i*KNB + j;
      nbr[e] = i; dist[e] = 0.0f; cval[e] = 0.0f;
    }
  } else if (bid < 1728) {
    int idx = (bid - 512)*256 + tid;
    if (idx < NKNOT*64) {
      int i = idx >> 6, g = idx & 63;
      float v = 0.0f;
      if (g < GG) {
        const float step = 10.0f/49.0f;
        const float coeff = -0.5f/(step*step);
        float d = (float)i * (10.0f/(float)(NKNOT-1));
        float dd = d - step*(float)g;
        v = __expf(coeff*dd*dd);
      }
      basis[idx] = f2b(v);
    } else {
      int r = idx - NKNOT*64;
      if (r < LL*WROW*64) {
        int l = r / (WROW*64); int rem = r - l*WROW*64;
        int n = rem >> 6, k = rem & 63;
        float v = (n < HD && k < GG) ? w1[(size_t)l*GG*HD + (size_t)k*HD + n] : 0.0f;
        w1b[r] = f2b(v);
      }
    }
  } else if (bid < 4128) {
    __shared__ float T[64][65];
    int r = bid - 1728;
    int w = r / 100; int rem = r - w*100;
    int ny = rem / 10, nz = rem - ny*10;
    int kind = w / 6, l = w - kind*6;
    const float* s = (kind == 0) ? l1w : (kind == 1) ? l2w : (kind == 2) ? ilw : w2;
    s += (size_t)l*360000;
    int n0 = ny*64, k0 = nz*64;
    int ta = tid & 63, tb = tid >> 6;
    #pragma unroll
    for (int p = 0; p < 16; ++p) {
      int k = k0 + p*4 + tb;
      int n = n0 + ta;
      T[p*4 + tb][ta] = (k < HD && n < HD) ? s[(size_t)k*HD + n] : 0.0f;
    }
    __syncthreads();
    #pragma unroll
    for (int p = 0; p < 16; ++p) {
      int n = n0 + p*4 + tb;
      int k = k0 + ta;
      if (k < WCOL)
        nwall[(size_t)w*WROW*WCOL + (size_t)n*WCOL + k] = f2b(T[ta][p*4 + tb]);
    }
  } else {
    int i = bid - 4128;
    int zi = z[i];
    for (int j = tid; j < WCOL; j += 256) {
      float v = (j < HD) ? emb[(size_t)zi*HD + j] : 0.0f;
      if (j < HD) h[(size_t)i*HD + j] = v;
      hb[(size_t)i*WCOL + j] = f2b(v);
    }
  }
}

// ---------------- tabA: ttab_all[l] = bf16(ssp(basis@w1[l]+b1[l])) ----------------
__global__ __launch_bounds__(256) void tabA_k(const short* __restrict__ basis,
    const short* __restrict__ w1b, const float* __restrict__ b1all,
    short* __restrict__ ttab_all) {
  const int MT = NKNOT/128;
  int l = blockIdx.x / MT;
  int mb = blockIdx.x - l*MT;
  const short* Bw = w1b + (size_t)l*WROW*64;
  short* outb = ttab_all + (size_t)l*NKNOT*WCOL;
  __shared__ __align__(16) short As[128*40];
  __shared__ __align__(16) short Bs[128*40];
  int tid = threadIdx.x;
  int lane = tid & 63, wv = tid >> 6;
  int wr = wv >> 1, wc = wv & 1;
  int col = lane & 15, quad = lane >> 4;
  int m0 = mb * 128;
  int n0 = blockIdx.y * 128;
  f32x4 acc[4][4] = {};
  for (int k0 = 0; k0 < 64; k0 += 32) {
    #pragma unroll
    for (int rep = 0; rep < 2; ++rep) {
      int s = tid + rep*256;
      int row = s >> 2, seg = s & 3;
      *(short8*)&As[row*40 + seg*8] =
          *(const short8*)(basis + (size_t)(m0 + row)*64 + k0 + seg*8);
      *(short8*)&Bs[row*40 + seg*8] =
          *(const short8*)(Bw + (size_t)(n0 + row)*64 + k0 + seg*8);
    }
    __syncthreads();
    short8 af[4], bf[4];
    #pragma unroll
    for (int mt = 0; mt < 4; ++mt)
      af[mt] = *(const short8*)&As[(wr*64 + mt*16 + col)*40 + quad*8];
    #pragma unroll
    for (int jt = 0; jt < 4; ++jt)
      bf[jt] = *(const short8*)&Bs[(wc*64 + jt*16 + col)*40 + quad*8];
    #pragma unroll
    for (int mt = 0; mt < 4; ++mt)
      #pragma unroll
      for (int jt = 0; jt < 4; ++jt)
        acc[mt][jt] = __builtin_amdgcn_mfma_f32_16x16x32_bf16(af[mt], bf[jt], acc[mt][jt], 0, 0, 0);
    __syncthreads();
  }
  #pragma unroll
  for (int jt = 0; jt < 4; ++jt) {
    int j = n0 + wc*64 + jt*16 + col;
    if (j >= WCOL) continue;
    float bj = (j < HD) ? b1all[(size_t)l*HD + j] : 0.0f;
    #pragma unroll
    for (int mt = 0; mt < 4; ++mt)
      #pragma unroll
      for (int r = 0; r < 4; ++r) {
        int row = m0 + wr*64 + mt*16 + quad*4 + r;
        short v = (j < HD) ? f2b(ssp_fast(acc[mt][jt][r] + bj)) : (short)0;
        outb[(size_t)row*WCOL + j] = v;
      }
  }
}

// ---------------- tabB: wtab_b[l] = bf16(ttab_all[l]@w2[l] + b2[l]); 128x128 tiles ----------------
__global__ __launch_bounds__(256) void tabB_k(const short* __restrict__ ttab_all,
    const short* __restrict__ nwall, const float* __restrict__ b2all,
    short* __restrict__ wtab_b) {
  const int MT = NKNOT/128;
  int l = blockIdx.x / MT;
  int mb = blockIdx.x - l*MT;
  const short* A  = ttab_all + (size_t)l*NKNOT*WCOL;
  const short* Bw = nwall + (size_t)(18 + l)*WROW*WCOL;   // kind=3 (w2)
  short* P = wtab_b + (size_t)l*NKNOT*HD;
  __shared__ __align__(16) short As[128*40];
  __shared__ __align__(16) short Bs[128*40];
  int tid = threadIdx.x;
  int lane = tid & 63, wv = tid >> 6;
  int wr = wv >> 1, wc = wv & 1;
  int col = lane & 15, quad = lane >> 4;
  int m0 = mb * 128;
  int n0 = blockIdx.y * 128;
  f32x4 acc[4][4] = {};
  for (int k0 = 0; k0 < WCOL; k0 += 32) {
    #pragma unroll
    for (int rep = 0; rep < 2; ++rep) {
      int s = tid + rep*256;
      int row = s >> 2, seg = s & 3;
      *(short8*)&As[row*40 + seg*8] =
          *(const short8*)(A + (size_t)(m0 + row)*WCOL + k0 + seg*8);
      *(short8*)&Bs[row*40 + seg*8] =
          *(const short8*)(Bw + (size_t)(n0 + row)*WCOL + k0 + seg*8);
    }
    __syncthreads();
    short8 af[4], bf[4];
    #pragma unroll
    for (int mt = 0; mt < 4; ++mt)
      af[mt] = *(const short8*)&As[(wr*64 + mt*16 + col)*40 + quad*8];
    #pragma unroll
    for (int jt = 0; jt < 4; ++jt)
      bf[jt] = *(const short8*)&Bs[(wc*64 + jt*16 + col)*40 + quad*8];
    #pragma unroll
    for (int mt = 0; mt < 4; ++mt)
      #pragma unroll
      for (int jt = 0; jt < 4; ++jt)
        acc[mt][jt] = __builtin_amdgcn_mfma_f32_16x16x32_bf16(af[mt], bf[jt], acc[mt][jt], 0, 0, 0);
    __syncthreads();
  }
  #pragma unroll
  for (int jt = 0; jt < 4; ++jt) {
    int j = n0 + wc*64 + jt*16 + col;
    if (j >= HD) continue;
    float bj = b2all[(size_t)l*HD + j];
    #pragma unroll
    for (int mt = 0; mt < 4; ++mt)
      #pragma unroll
      for (int r = 0; r < 4; ++r) {
        int row = m0 + wr*64 + mt*16 + quad*4 + r;
        P[(size_t)row*HD + j] = f2b(acc[mt][jt][r] + bj);
      }
  }
}

// ---------------- gather: msg_b[node] = bf16(sum_e C_e * Wtab(d_e) (.) x1[nbr_e]) ----------------
// 320 threads x 2 cols (4B loads): 5 waves/block for latency hiding on the L2/L3 edge loop
__global__ __launch_bounds__(320) void gather_k(const short* __restrict__ tabb,
    const float* __restrict__ cval, const int* __restrict__ nbr,
    const float* __restrict__ dist, const short* __restrict__ x1b,
    short* __restrict__ msgb) {
  __shared__ float cvs[64];
  __shared__ int nbs[64];
  __shared__ int tix[64];
  __shared__ float tfr[64];
  int node = blockIdx.x, tid = threadIdx.x;
  if (tid < 64) {
    int e = node*KNB + tid;
    cvs[tid] = cval[e];
    nbs[tid] = nbr[e];
    float u = dist[e] * ((float)(NKNOT-1)/10.0f);
    int i = (int)u;
    if (i > NKNOT-2) i = NKNOT-2;
    tix[tid] = i;
    tfr[tid] = u - (float)i;
  }
  __syncthreads();
  int j = tid*2;                   // j in [0,640)
  if (j >= HD) {                   // j = 600..638: zero the bf16 pads (4B each)
    *(unsigned*)&msgb[(size_t)node*WCOL + j] = 0u;
    return;
  }
  float s0 = 0.f, s1 = 0.f;
  #pragma unroll 4
  for (int e = 0; e < KNB; ++e) {
    float Ce = cvs[e];
    if (Ce == 0.0f) continue;
    const short* w0 = tabb + (size_t)tix[e]*HD + j;
    float f = tfr[e];
    unsigned wa = *(const unsigned*)w0;
    unsigned wb = *(const unsigned*)(w0 + HD);
    unsigned xv = *(const unsigned*)(x1b + (size_t)nbs[e]*WCOL + j);
    float a0 = b2f(wa & 0xffffu), a1 = b2f(wa >> 16);
    float b0 = b2f(wb & 0xffffu), b1 = b2f(wb >> 16);
    float x0 = b2f(xv & 0xffffu), x1v = b2f(xv >> 16);
    s0 += Ce * (a0 + f*(b0 - a0)) * x0;
    s1 += Ce * (a1 + f*(b1 - a1)) * x1v;
  }
  unsigned pack = (unsigned)(unsigned short)f2b(s0) |
                  ((unsigned)(unsigned short)f2b(s1) << 16);
  *(unsigned*)&msgb[(size_t)node*WCOL + j] = pack;
}

// ---------------- fused node GEMM: 32x64 tile, 8 waves, 2-way split-K, BK=64 ----------------
// grid (32, 10), 512 threads. Group g handles K half [g*320, +320) as 5 steps of 64.
// Staging via global_load_lds (16B/lane DMA): LINEAR LDS dest; XOR-swizzled GLOBAL
// source granule (gc ^= row&7); fragment reads apply the same involution -> conflict-free
// (16-lane fragment read spreads over 8 granule slots, 2 lanes each = free 2-way).
// MODE 0: outb = bf16(acc), pads zero               (x1 -> x1_b)
// MODE 1: outb = bf16(ssp(acc+bias)), pads zero     (lin2 -> mtmp_b)
// MODE 2: hacc += acc+bias; outb = bf16(hacc')      (int_lin residual -> h, h_b)
template<int MODE>
__global__ __launch_bounds__(512) void gemm_node_k(
    const short* __restrict__ A, const short* __restrict__ Bw,
    const float* __restrict__ bias,
    short* __restrict__ outb, float* __restrict__ hacc) {
  __shared__ __align__(16) short As[2][2][32*64];   // [group][buf] 4 KB, linear
  __shared__ __align__(16) short Bs[2][2][64*64];   // [group][buf] 8 KB, linear
  __shared__ __align__(16) float red[256*8];
  int tid = threadIdx.x;
  int g = tid >> 8;                 // K-split group (0 or 1)
  int t = tid & 255;
  int lane = t & 63, wv = t >> 6;   // wave-in-group 0..3
  int col = lane & 15, quad = lane >> 4;
  int m0 = blockIdx.x * 32;
  int n0 = blockIdx.y * 64;
  const int kb = g * 320;
  // staging roles: per wave per step, 1 A-issue + 2 B-issues (64 lanes x 16B each)
  int a_gi = wv*64 + lane;                       // A granule 0..255
  int a_row = a_gi >> 3;
  int a_gc = (a_gi & 7) ^ (a_row & 7);           // swizzled source granule
  const short* a_src = A + (size_t)(m0 + a_row)*WCOL + kb + a_gc*8;
  int b_gi0 = wv*128 + lane;                     // B granules 0..511
  int b_row0 = b_gi0 >> 3;
  int b_gc0 = (b_gi0 & 7) ^ (b_row0 & 7);
  const short* b_src0 = Bw + (size_t)(n0 + b_row0)*WCOL + kb + b_gc0*8;
  int b_gi1 = b_gi0 + 64;
  int b_row1 = b_gi1 >> 3;
  int b_gc1 = (b_gi1 & 7) ^ (b_row1 & 7);
  const short* b_src1 = Bw + (size_t)(n0 + b_row1)*WCOL + kb + b_gc1*8;
  short* a_dst[2]  = { &As[g][0][a_gi*8],  &As[g][1][a_gi*8] };
  short* b_dst0[2] = { &Bs[g][0][b_gi0*8], &Bs[g][1][b_gi0*8] };
  short* b_dst1[2] = { &Bs[g][0][b_gi1*8], &Bs[g][1][b_gi1*8] };
  GLOAD16(a_src, a_dst[0]);
  GLOAD16(b_src0, b_dst0[0]);
  GLOAD16(b_src1, b_dst1[0]);
  __syncthreads();                               // vmcnt(0) drain -> buf0 ready
  f32x4 acc[2] = {};
  #pragma unroll
  for (int kk = 0; kk < 5; ++kk) {
    const int cur = kk & 1, nxt = cur ^ 1;
    if (kk < 4) {                                // DMA next step while computing
      GLOAD16(a_src + (kk+1)*64, a_dst[nxt]);
      GLOAD16(b_src0 + (kk+1)*64, b_dst0[nxt]);
      GLOAD16(b_src1 + (kk+1)*64, b_dst1[nxt]);
    }
    #pragma unroll
    for (int kh = 0; kh < 2; ++kh) {
      int brow = wv*16 + col;
      int bgr = brow*8 + ((kh*4 + quad) ^ (brow & 7));
      short8 bf = *(const short8*)&Bs[g][cur][bgr*8];
      #pragma unroll
      for (int mt = 0; mt < 2; ++mt) {
        int arow = mt*16 + col;
        int agr = arow*8 + ((kh*4 + quad) ^ (arow & 7));
        short8 af = *(const short8*)&As[g][cur][agr*8];
        acc[mt] = __builtin_amdgcn_mfma_f32_16x16x32_bf16(af, bf, acc[mt], 0, 0, 0);
      }
    }
    __syncthreads();                             // drains DMA -> nxt ready
  }
  // cross-group reduction: group 1 -> LDS, group 0 adds
  if (g) {
    #pragma unroll
    for (int mt = 0; mt < 2; ++mt)
      *(f32x4*)&red[(t*2 + mt)*4] = acc[mt];
  }
  __syncthreads();
  if (g) return;
  #pragma unroll
  for (int mt = 0; mt < 2; ++mt)
    acc[mt] += *(const f32x4*)&red[(t*2 + mt)*4];
  int j = n0 + wv*16 + col;
  if (MODE == 0) {
    #pragma unroll
    for (int mt = 0; mt < 2; ++mt)
      #pragma unroll
      for (int r = 0; r < 4; ++r) {
        int row = m0 + mt*16 + quad*4 + r;
        outb[(size_t)row*WCOL + j] = (j < HD) ? f2b(acc[mt][r]) : (short)0;
      }
  } else if (MODE == 1) {
    float bj = (j < HD) ? bias[j] : 0.0f;
    #pragma unroll
    for (int mt = 0; mt < 2; ++mt)
      #pragma unroll
      for (int r = 0; r < 4; ++r) {
        int row = m0 + mt*16 + quad*4 + r;
        outb[(size_t)row*WCOL + j] = (j < HD) ? f2b(ssp_fast(acc[mt][r] + bj)) : (short)0;
      }
  } else {
    #pragma unroll
    for (int mt = 0; mt < 2; ++mt)
      #pragma unroll
      for (int r = 0; r < 4; ++r) {
        int row = m0 + mt*16 + quad*4 + r;
        if (j < HD) {
          float nv = hacc[(size_t)row*HD + j] + acc[mt][r] + bias[j];
          hacc[(size_t)row*HD + j] = nv;
          outb[(size_t)row*WCOL + j] = f2b(nv);
        } else {
          outb[(size_t)row*WCOL + j] = 0;
        }
      }
  }
}

// ---------------- pooling: grid (8, 10); 4-way n-split x 64 cols ----------------
__global__ __launch_bounds__(256) void pool_mean_k(const float* __restrict__ h,
                                                   float* __restrict__ pooled) {
  __shared__ float red[4][64];
  int b = blockIdx.x;
  int cl = threadIdx.x & 63, q = threadIdx.x >> 6;
  int c = blockIdx.y*64 + cl;
  float s = 0.0f;
  if (c < HD) {
    int n0 = q*32;
    #pragma unroll 8
    for (int n = n0; n < n0 + 32; ++n)
      s += h[(size_t)(b*NPG + n)*HD + c];
  }
  red[q][cl] = s;
  __syncthreads();
  if (q == 0 && c < HD)
    pooled[(size_t)b*HD + c] =
        (red[0][cl] + red[1][cl] + red[2][cl] + red[3][cl]) * (1.0f/128.0f);
}

// grid (10, 8): 64 j per block, 4-way c-split, LDS reduce
__global__ __launch_bounds__(256) void pool_out_k(const float* __restrict__ pooled,
    const float* __restrict__ pw, const float* __restrict__ pb,
    float* __restrict__ out) {
  __shared__ float red[4][64];
  int b = blockIdx.y;
  int tid = threadIdx.x;
  int jl = tid & 63, q = tid >> 6;
  int j = blockIdx.x*64 + jl;
  float s = 0.0f;
  if (j < HD) {
    int c0 = q*150, c1 = c0 + 150;
    for (int c = c0; c < c1; ++c)
      s += pooled[(size_t)b*HD + c] * pw[(size_t)c*HD + j];
  }
  red[q][jl] = s;
  __syncthreads();
  if (q == 0 && j < HD)
    out[(size_t)b*HD + j] = red[0][jl] + red[1][jl] + red[2][jl] + red[3][jl] + pb[j];
}

// ---------------- launch ----------------
extern "C" void kernel_launch(void* const* d_in, const int* in_sizes, int n_in,
                              void* d_out, int out_size, void* d_ws, size_t ws_size,
                              hipStream_t stream) {
  const int*   z    = (const int*)d_in[0];
  const float* pos  = (const float*)d_in[1];
  const float* emb  = (const float*)d_in[2];
  const float* w1   = (const float*)d_in[3];
  const float* b1   = (const float*)d_in[4];
  const float* w2   = (const float*)d_in[5];
  const float* b2   = (const float*)d_in[6];
  const float* l1w  = (const float*)d_in[7];
  const float* l2w  = (const float*)d_in[8];
  const float* l2b  = (const float*)d_in[9];
  const float* ilw  = (const float*)d_in[10];
  const float* ilb  = (const float*)d_in[11];
  const float* pw   = (const float*)d_in[12];
  const float* pb   = (const float*)d_in[13];
  float* ws = (float*)d_ws;
  int*   nbr   = (int*)ws;                   // 65536
  float* cv    = ws + 65536;                 // 65536
  float* dist  = ws + 131072;                // 65536
  float* pooled= ws + 196608;                // 8192
  float* h     = ws + 204800;                // 614400
  short* h_b   = (short*)(ws + 819200);      // 1024*640 sh = 327680 f
  short* msg_b = (short*)(ws + 1146880);     // 327680 f
  short* mtmp_b= (short*)(ws + 1474560);     // 327680 f
  short* x1_b  = (short*)(ws + 1802240);     // 327680 f
  short* basis = (short*)(ws + 2129920);     // 32768 f
  short* ttab  = (short*)(ws + 2162688);     // 1966080 f
  short* wtab_b= (short*)(ws + 4128768);     // 1843200 f
  short* w1b   = (short*)(ws + 5971968);     // 122880 f
  short* nwall = (short*)(ws + 6094848);     // 4915200 f
  float* out   = (float*)d_out;

  const size_t WSZ = (size_t)WROW*WCOL;

  prolog_k<<<5152, 256, 0, stream>>>(pos, nbr, dist, cv,
      w1, basis, w1b, l1w, l2w, ilw, w2, nwall, z, emb, h, h_b);
  tabA_k<<<dim3(LL*(NKNOT/128), 5), 256, 0, stream>>>(basis, w1b, b1, ttab);
  tabB_k<<<dim3(LL*(NKNOT/128), 5), 256, 0, stream>>>(ttab, nwall, b2, wtab_b);

  dim3 gn(32, 10);
  for (int l = 0; l < LL; ++l) {
    // x1_b = bf16(h @ lin1_w[l])
    gemm_node_k<0><<<gn, 512, 0, stream>>>(h_b, nwall + (size_t)(0*6 + l)*WSZ,
        nullptr, x1_b, nullptr);
    // msg_b[node] = bf16(sum_e C_e * Wtab(d_e) (.) x1[nbr_e])
    gather_k<<<NN, 320, 0, stream>>>(wtab_b + (size_t)l*NKNOT*HD, cv, nbr, dist, x1_b, msg_b);
    // mtmp_b = bf16(ssp(msg @ lin2_w[l] + lin2_b[l]))
    gemm_node_k<1><<<gn, 512, 0, stream>>>(msg_b, nwall + (size_t)(1*6 + l)*WSZ,
        l2b + (size_t)l*HD, mtmp_b, nullptr);
    // h += mtmp @ int_lin_w[l] + int_lin_b[l]; h_b = bf16(h)
    gemm_node_k<2><<<gn, 512, 0, stream>>>(mtmp_b, nwall + (size_t)(2*6 + l)*WSZ,
        ilb + (size_t)l*HD, h_b, h);
  }
  pool_mean_k<<<dim3(NB, 10), 256, 0, stream>>>(h, pooled);
  pool_out_k<<<dim3(10, NB), 256, 0, stream>>>(pooled, pw, pb, out);
}

// Round 11
// 405.044 us; speedup vs baseline: 9.4664x; 1.0095x over previous
//
#include <hip/hip_runtime.h>
#include <cmath>

#define NB   8
#define NPG  128
#define NN   1024
#define KNB  64
#define HD   600
#define GG   50
#define LL   6
#define WROW 640          // padded weight rows (n)
#define WCOL 640          // padded weight cols (k) — 640 for clean BK=64 split-K
#define NKNOT 1024        // W(d) table knots over [0,10]

typedef __attribute__((ext_vector_type(8))) short short8;
typedef __attribute__((ext_vector_type(4))) float f32x4;

// async global->LDS DMA, 16B per lane (wave-uniform LDS base + lane*16)
#define GLOAD16(gsrc, ldst) \
  __builtin_amdgcn_global_load_lds( \
      (const __attribute__((address_space(1))) void*)(gsrc), \
      (__attribute__((address_space(3))) void*)(ldst), 16, 0, 0)

__device__ __forceinline__ short f2b(float f) {
  union { float f; unsigned u; } v; v.f = f;
  unsigned u = v.u;
  u += 0x7fffu + ((u >> 16) & 1u);
  return (short)(u >> 16);
}

__device__ __forceinline__ float b2f(unsigned us) {
  union { unsigned u; float f; } v; v.u = us << 16; return v.f;
}

// fast shifted softplus: max(x,0)+log(1+e^-|x|)-ln2
__device__ __forceinline__ float ssp_fast(float x) {
  return fmaxf(x, 0.0f) + __logf(1.0f + __expf(-fabsf(x))) - 0.69314718055994531f;
}

// ---------------- merged prolog: build_graph + prep + conv_all + embed (+pooled zero) ----------------
__global__ __launch_bounds__(256) void prolog_k(
    const float* __restrict__ pos, int* __restrict__ nbr,
    float* __restrict__ dist, float* __restrict__ cval,
    const float* __restrict__ w1, short* __restrict__ basis, short* __restrict__ w1b,
    const float* __restrict__ l1w, const float* __restrict__ l2w,
    const float* __restrict__ ilw, const float* __restrict__ w2,
    short* __restrict__ nwall,
    const int* __restrict__ z, const float* __restrict__ emb,
    float* __restrict__ h, short* __restrict__ hb, float* __restrict__ pooled) {
  int bid = blockIdx.x;
  int tid = threadIdx.x;
  if (bid < 512) {
#pragma clang fp contract(off)
    __shared__ float d2s[2][128];
    __shared__ int scnt[2];
    int sub = tid >> 7;
    int j = tid & 127;
    int i = bid*2 + sub;
    int li = i & 127;
    int base = i - li;
    if (j == 0) scnt[sub] = 0;
    float px = pos[3*i], py = pos[3*i+1], pz = pos[3*i+2];
    int gj = base + j;
    float dx = px - pos[3*gj], dy = py - pos[3*gj+1], dz = pz - pos[3*gj+2];
    float d2 = dx*dx + dy*dy + dz*dz;
    bool valid = (j != li) && (d2 <= 100.0f);
    d2s[sub][j] = valid ? d2 : 3.0e38f;
    __syncthreads();
    if (valid) {
      atomicAdd(&scnt[sub], 1);
      int rank = 0;
      for (int j2 = 0; j2 < 128; ++j2) {
        float o = d2s[sub][j2];
        rank += (o < d2 || (o == d2 && j2 < j)) ? 1 : 0;
      }
      if (rank < KNB) {
        int e = i*KNB + rank;
        nbr[e] = gj;
        float d = sqrtf(d2);
        dist[e] = d;
        cval[e] = 0.5f * (cosf(d * 0.31415926535897931f) + 1.0f);
      }
    }
    __syncthreads();
    int cnt = scnt[sub]; if (cnt > KNB) cnt = KNB;
    if (j < KNB && j >= cnt) {
      int e = i*KNB + j;
      nbr[e] = i; dist[e] = 0.0f; cval[e] = 0.0f;
    }
  } else if (bid < 1728) {
    int idx = (bid - 512)*256 + tid;
    if (idx < NKNOT*64) {
      int i = idx >> 6, g = idx & 63;
      float v = 0.0f;
      if (g < GG) {
        const float step = 10.0f/49.0f;
        const float coeff = -0.5f/(step*step);
        float d = (float)i * (10.0f/(float)(NKNOT-1));
        float dd = d - step*(float)g;
        v = __expf(coeff*dd*dd);
      }
      basis[idx] = f2b(v);
    } else {
      int r = idx - NKNOT*64;
      if (r < LL*WROW*64) {
        int l = r / (WROW*64); int rem = r - l*WROW*64;
        int n = rem >> 6, k = rem & 63;
        float v = (n < HD && k < GG) ? w1[(size_t)l*GG*HD + (size_t)k*HD + n] : 0.0f;
        w1b[r] = f2b(v);
      }
    }
  } else if (bid < 4128) {
    __shared__ float T[64][65];
    int r = bid - 1728;
    int w = r / 100; int rem = r - w*100;
    int ny = rem / 10, nz = rem - ny*10;
    int kind = w / 6, l = w - kind*6;
    const float* s = (kind == 0) ? l1w : (kind == 1) ? l2w : (kind == 2) ? ilw : w2;
    s += (size_t)l*360000;
    int n0 = ny*64, k0 = nz*64;
    int ta = tid & 63, tb = tid >> 6;
    #pragma unroll
    for (int p = 0; p < 16; ++p) {
      int k = k0 + p*4 + tb;
      int n = n0 + ta;
      T[p*4 + tb][ta] = (k < HD && n < HD) ? s[(size_t)k*HD + n] : 0.0f;
    }
    __syncthreads();
    #pragma unroll
    for (int p = 0; p < 16; ++p) {
      int n = n0 + p*4 + tb;
      int k = k0 + ta;
      if (k < WCOL)
        nwall[(size_t)w*WROW*WCOL + (size_t)n*WCOL + k] = f2b(T[ta][p*4 + tb]);
    }
  } else {
    int i = bid - 4128;
    int zi = z[i];
    for (int j = tid; j < WCOL; j += 256) {
      float v = (j < HD) ? emb[(size_t)zi*HD + j] : 0.0f;
      if (j < HD) h[(size_t)i*HD + j] = v;
      hb[(size_t)i*WCOL + j] = f2b(v);
    }
    if (i < NB) {                    // zero pooled accumulator (fused pool, MODE 3)
      for (int c = tid; c < HD; c += 256) pooled[(size_t)i*HD + c] = 0.0f;
    }
  }
}

// ---------------- tabA: ttab_all[l] = bf16(ssp(basis@w1[l]+b1[l])) ----------------
__global__ __launch_bounds__(256) void tabA_k(const short* __restrict__ basis,
    const short* __restrict__ w1b, const float* __restrict__ b1all,
    short* __restrict__ ttab_all) {
  const int MT = NKNOT/128;
  int l = blockIdx.x / MT;
  int mb = blockIdx.x - l*MT;
  const short* Bw = w1b + (size_t)l*WROW*64;
  short* outb = ttab_all + (size_t)l*NKNOT*WCOL;
  __shared__ __align__(16) short As[128*40];
  __shared__ __align__(16) short Bs[128*40];
  int tid = threadIdx.x;
  int lane = tid & 63, wv = tid >> 6;
  int wr = wv >> 1, wc = wv & 1;
  int col = lane & 15, quad = lane >> 4;
  int m0 = mb * 128;
  int n0 = blockIdx.y * 128;
  f32x4 acc[4][4] = {};
  for (int k0 = 0; k0 < 64; k0 += 32) {
    #pragma unroll
    for (int rep = 0; rep < 2; ++rep) {
      int s = tid + rep*256;
      int row = s >> 2, seg = s & 3;
      *(short8*)&As[row*40 + seg*8] =
          *(const short8*)(basis + (size_t)(m0 + row)*64 + k0 + seg*8);
      *(short8*)&Bs[row*40 + seg*8] =
          *(const short8*)(Bw + (size_t)(n0 + row)*64 + k0 + seg*8);
    }
    __syncthreads();
    short8 af[4], bf[4];
    #pragma unroll
    for (int mt = 0; mt < 4; ++mt)
      af[mt] = *(const short8*)&As[(wr*64 + mt*16 + col)*40 + quad*8];
    #pragma unroll
    for (int jt = 0; jt < 4; ++jt)
      bf[jt] = *(const short8*)&Bs[(wc*64 + jt*16 + col)*40 + quad*8];
    #pragma unroll
    for (int mt = 0; mt < 4; ++mt)
      #pragma unroll
      for (int jt = 0; jt < 4; ++jt)
        acc[mt][jt] = __builtin_amdgcn_mfma_f32_16x16x32_bf16(af[mt], bf[jt], acc[mt][jt], 0, 0, 0);
    __syncthreads();
  }
  #pragma unroll
  for (int jt = 0; jt < 4; ++jt) {
    int j = n0 + wc*64 + jt*16 + col;
    if (j >= WCOL) continue;
    float bj = (j < HD) ? b1all[(size_t)l*HD + j] : 0.0f;
    #pragma unroll
    for (int mt = 0; mt < 4; ++mt)
      #pragma unroll
      for (int r = 0; r < 4; ++r) {
        int row = m0 + wr*64 + mt*16 + quad*4 + r;
        short v = (j < HD) ? f2b(ssp_fast(acc[mt][jt][r] + bj)) : (short)0;
        outb[(size_t)row*WCOL + j] = v;
      }
  }
}

// ---------------- tabB: wtab_b[l] = bf16(ttab_all[l]@w2[l] + b2[l]); 128x128 tiles ----------------
__global__ __launch_bounds__(256) void tabB_k(const short* __restrict__ ttab_all,
    const short* __restrict__ nwall, const float* __restrict__ b2all,
    short* __restrict__ wtab_b) {
  const int MT = NKNOT/128;
  int l = blockIdx.x / MT;
  int mb = blockIdx.x - l*MT;
  const short* A  = ttab_all + (size_t)l*NKNOT*WCOL;
  const short* Bw = nwall + (size_t)(18 + l)*WROW*WCOL;   // kind=3 (w2)
  short* P = wtab_b + (size_t)l*NKNOT*HD;
  __shared__ __align__(16) short As[128*40];
  __shared__ __align__(16) short Bs[128*40];
  int tid = threadIdx.x;
  int lane = tid & 63, wv = tid >> 6;
  int wr = wv >> 1, wc = wv & 1;
  int col = lane & 15, quad = lane >> 4;
  int m0 = mb * 128;
  int n0 = blockIdx.y * 128;
  f32x4 acc[4][4] = {};
  for (int k0 = 0; k0 < WCOL; k0 += 32) {
    #pragma unroll
    for (int rep = 0; rep < 2; ++rep) {
      int s = tid + rep*256;
      int row = s >> 2, seg = s & 3;
      *(short8*)&As[row*40 + seg*8] =
          *(const short8*)(A + (size_t)(m0 + row)*WCOL + k0 + seg*8);
      *(short8*)&Bs[row*40 + seg*8] =
          *(const short8*)(Bw + (size_t)(n0 + row)*WCOL + k0 + seg*8);
    }
    __syncthreads();
    short8 af[4], bf[4];
    #pragma unroll
    for (int mt = 0; mt < 4; ++mt)
      af[mt] = *(const short8*)&As[(wr*64 + mt*16 + col)*40 + quad*8];
    #pragma unroll
    for (int jt = 0; jt < 4; ++jt)
      bf[jt] = *(const short8*)&Bs[(wc*64 + jt*16 + col)*40 + quad*8];
    #pragma unroll
    for (int mt = 0; mt < 4; ++mt)
      #pragma unroll
      for (int jt = 0; jt < 4; ++jt)
        acc[mt][jt] = __builtin_amdgcn_mfma_f32_16x16x32_bf16(af[mt], bf[jt], acc[mt][jt], 0, 0, 0);
    __syncthreads();
  }
  #pragma unroll
  for (int jt = 0; jt < 4; ++jt) {
    int j = n0 + wc*64 + jt*16 + col;
    if (j >= HD) continue;
    float bj = b2all[(size_t)l*HD + j];
    #pragma unroll
    for (int mt = 0; mt < 4; ++mt)
      #pragma unroll
      for (int r = 0; r < 4; ++r) {
        int row = m0 + wr*64 + mt*16 + quad*4 + r;
        P[(size_t)row*HD + j] = f2b(acc[mt][jt][r] + bj);
      }
  }
}

// ---------------- gather: msg_b[node] = bf16(sum_e C_e * Wtab(d_e) (.) x1[nbr_e]) ----------------
// 320 threads x 2 cols (4B loads): 5 waves/block for latency hiding on the L2/L3 edge loop
__global__ __launch_bounds__(320) void gather_k(const short* __restrict__ tabb,
    const float* __restrict__ cval, const int* __restrict__ nbr,
    const float* __restrict__ dist, const short* __restrict__ x1b,
    short* __restrict__ msgb) {
  __shared__ float cvs[64];
  __shared__ int nbs[64];
  __shared__ int tix[64];
  __shared__ float tfr[64];
  int node = blockIdx.x, tid = threadIdx.x;
  if (tid < 64) {
    int e = node*KNB + tid;
    cvs[tid] = cval[e];
    nbs[tid] = nbr[e];
    float u = dist[e] * ((float)(NKNOT-1)/10.0f);
    int i = (int)u;
    if (i > NKNOT-2) i = NKNOT-2;
    tix[tid] = i;
    tfr[tid] = u - (float)i;
  }
  __syncthreads();
  int j = tid*2;                   // j in [0,640)
  if (j >= HD) {                   // j = 600..638: zero the bf16 pads (4B each)
    *(unsigned*)&msgb[(size_t)node*WCOL + j] = 0u;
    return;
  }
  float s0 = 0.f, s1 = 0.f;
  #pragma unroll 4
  for (int e = 0; e < KNB; ++e) {
    float Ce = cvs[e];
    if (Ce == 0.0f) continue;
    const short* w0 = tabb + (size_t)tix[e]*HD + j;
    float f = tfr[e];
    unsigned wa = *(const unsigned*)w0;
    unsigned wb = *(const unsigned*)(w0 + HD);
    unsigned xv = *(const unsigned*)(x1b + (size_t)nbs[e]*WCOL + j);
    float a0 = b2f(wa & 0xffffu), a1 = b2f(wa >> 16);
    float b0 = b2f(wb & 0xffffu), b1 = b2f(wb >> 16);
    float x0 = b2f(xv & 0xffffu), x1v = b2f(xv >> 16);
    s0 += Ce * (a0 + f*(b0 - a0)) * x0;
    s1 += Ce * (a1 + f*(b1 - a1)) * x1v;
  }
  unsigned pack = (unsigned)(unsigned short)f2b(s0) |
                  ((unsigned)(unsigned short)f2b(s1) << 16);
  *(unsigned*)&msgb[(size_t)node*WCOL + j] = pack;
}

// ---------------- fused node GEMM: 32x64 tile, 8 waves, 2-way split-K, BK=64 ----------------
// grid (32, 10), 512 threads. global_load_lds swizzled staging (see R9 notes).
// Symmetric epilogue: both groups write acc->red, each group stores its mt=g fragment.
// MODE 0: outb = bf16(acc), pads zero               (x1 -> x1_b)
// MODE 1: outb = bf16(ssp(acc+bias)), pads zero     (lin2 -> mtmp_b)
// MODE 2: hacc += acc+bias; outb = bf16(hacc')      (int_lin residual -> h, h_b)
// MODE 3: MODE 2 + atomic mean-pool accumulation into pooled (last layer)
template<int MODE>
__global__ __launch_bounds__(512) void gemm_node_k(
    const short* __restrict__ A, const short* __restrict__ Bw,
    const float* __restrict__ bias,
    short* __restrict__ outb, float* __restrict__ hacc, float* __restrict__ pooled) {
  __shared__ __align__(16) short As[2][2][32*64];   // [group][buf] 4 KB, linear
  __shared__ __align__(16) short Bs[2][2][64*64];   // [group][buf] 8 KB, linear
  __shared__ __align__(16) float red[2][256*8];     // both groups' acc
  int tid = threadIdx.x;
  int g = tid >> 8;                 // K-split group (0 or 1)
  int t = tid & 255;
  int lane = t & 63, wv = t >> 6;   // wave-in-group 0..3
  int col = lane & 15, quad = lane >> 4;
  int m0 = blockIdx.x * 32;
  int n0 = blockIdx.y * 64;
  const int kb = g * 320;
  // staging roles: per wave per step, 1 A-issue + 2 B-issues (64 lanes x 16B each)
  int a_gi = wv*64 + lane;                       // A granule 0..255
  int a_row = a_gi >> 3;
  int a_gc = (a_gi & 7) ^ (a_row & 7);           // swizzled source granule
  const short* a_src = A + (size_t)(m0 + a_row)*WCOL + kb + a_gc*8;
  int b_gi0 = wv*128 + lane;                     // B granules 0..511
  int b_row0 = b_gi0 >> 3;
  int b_gc0 = (b_gi0 & 7) ^ (b_row0 & 7);
  const short* b_src0 = Bw + (size_t)(n0 + b_row0)*WCOL + kb + b_gc0*8;
  int b_gi1 = b_gi0 + 64;
  int b_row1 = b_gi1 >> 3;
  int b_gc1 = (b_gi1 & 7) ^ (b_row1 & 7);
  const short* b_src1 = Bw + (size_t)(n0 + b_row1)*WCOL + kb + b_gc1*8;
  short* a_dst[2]  = { &As[g][0][a_gi*8],  &As[g][1][a_gi*8] };
  short* b_dst0[2] = { &Bs[g][0][b_gi0*8], &Bs[g][1][b_gi0*8] };
  short* b_dst1[2] = { &Bs[g][0][b_gi1*8], &Bs[g][1][b_gi1*8] };
  GLOAD16(a_src, a_dst[0]);
  GLOAD16(b_src0, b_dst0[0]);
  GLOAD16(b_src1, b_dst1[0]);
  __syncthreads();                               // vmcnt(0) drain -> buf0 ready
  f32x4 acc[2] = {};
  #pragma unroll
  for (int kk = 0; kk < 5; ++kk) {
    const int cur = kk & 1, nxt = cur ^ 1;
    if (kk < 4) {                                // DMA next step while computing
      GLOAD16(a_src + (kk+1)*64, a_dst[nxt]);
      GLOAD16(b_src0 + (kk+1)*64, b_dst0[nxt]);
      GLOAD16(b_src1 + (kk+1)*64, b_dst1[nxt]);
    }
    #pragma unroll
    for (int kh = 0; kh < 2; ++kh) {
      int brow = wv*16 + col;
      int bgr = brow*8 + ((kh*4 + quad) ^ (brow & 7));
      short8 bf = *(const short8*)&Bs[g][cur][bgr*8];
      #pragma unroll
      for (int mt = 0; mt < 2; ++mt) {
        int arow = mt*16 + col;
        int agr = arow*8 + ((kh*4 + quad) ^ (arow & 7));
        short8 af = *(const short8*)&As[g][cur][agr*8];
        acc[mt] = __builtin_amdgcn_mfma_f32_16x16x32_bf16(af, bf, acc[mt], 0, 0, 0);
      }
    }
    __syncthreads();                             // drains DMA -> nxt ready
  }
  // symmetric cross-group reduction: both groups publish, each stores mt=g half
  #pragma unroll
  for (int mt = 0; mt < 2; ++mt)
    *(f32x4*)&red[g][(t*2 + mt)*4] = acc[mt];
  __syncthreads();
  const int mt = g;                              // fragment this group stores
  f32x4 v = *(const f32x4*)&red[0][(t*2 + mt)*4];
  v += *(const f32x4*)&red[1][(t*2 + mt)*4];
  int j = n0 + wv*16 + col;
  if (MODE == 0) {
    #pragma unroll
    for (int r = 0; r < 4; ++r) {
      int row = m0 + mt*16 + quad*4 + r;
      outb[(size_t)row*WCOL + j] = (j < HD) ? f2b(v[r]) : (short)0;
    }
  } else if (MODE == 1) {
    float bj = (j < HD) ? bias[j] : 0.0f;
    #pragma unroll
    for (int r = 0; r < 4; ++r) {
      int row = m0 + mt*16 + quad*4 + r;
      outb[(size_t)row*WCOL + j] = (j < HD) ? f2b(ssp_fast(v[r] + bj)) : (short)0;
    }
  } else {
    float psum = 0.0f;
    #pragma unroll
    for (int r = 0; r < 4; ++r) {
      int row = m0 + mt*16 + quad*4 + r;
      if (j < HD) {
        float nv = hacc[(size_t)row*HD + j] + v[r] + bias[j];
        hacc[(size_t)row*HD + j] = nv;
        outb[(size_t)row*WCOL + j] = f2b(nv);
        psum += nv;
      } else {
        outb[(size_t)row*WCOL + j] = 0;
      }
    }
    if (MODE == 3 && j < HD) {
      int b = m0 >> 7;                           // graph index (32-row tile never straddles)
      atomicAdd(&pooled[(size_t)b*HD + j], psum * (1.0f/128.0f));
    }
  }
}

// grid (10, 8): 64 j per block, 4-way c-split, LDS reduce
__global__ __launch_bounds__(256) void pool_out_k(const float* __restrict__ pooled,
    const float* __restrict__ pw, const float* __restrict__ pb,
    float* __restrict__ out) {
  __shared__ float red[4][64];
  int b = blockIdx.y;
  int tid = threadIdx.x;
  int jl = tid & 63, q = tid >> 6;
  int j = blockIdx.x*64 + jl;
  float s = 0.0f;
  if (j < HD) {
    int c0 = q*150, c1 = c0 + 150;
    for (int c = c0; c < c1; ++c)
      s += pooled[(size_t)b*HD + c] * pw[(size_t)c*HD + j];
  }
  red[q][jl] = s;
  __syncthreads();
  if (q == 0 && j < HD)
    out[(size_t)b*HD + j] = red[0][jl] + red[1][jl] + red[2][jl] + red[3][jl] + pb[j];
}

// ---------------- launch ----------------
extern "C" void kernel_launch(void* const* d_in, const int* in_sizes, int n_in,
                              void* d_out, int out_size, void* d_ws, size_t ws_size,
                              hipStream_t stream) {
  const int*   z    = (const int*)d_in[0];
  const float* pos  = (const float*)d_in[1];
  const float* emb  = (const float*)d_in[2];
  const float* w1   = (const float*)d_in[3];
  const float* b1   = (const float*)d_in[4];
  const float* w2   = (const float*)d_in[5];
  const float* b2   = (const float*)d_in[6];
  const float* l1w  = (const float*)d_in[7];
  const float* l2w  = (const float*)d_in[8];
  const float* l2b  = (const float*)d_in[9];
  const float* ilw  = (const float*)d_in[10];
  const float* ilb  = (const float*)d_in[11];
  const float* pw   = (const float*)d_in[12];
  const float* pb   = (const float*)d_in[13];
  float* ws = (float*)d_ws;
  int*   nbr   = (int*)ws;                   // 65536
  float* cv    = ws + 65536;                 // 65536
  float* dist  = ws + 131072;                // 65536
  float* pooled= ws + 196608;                // 8192
  float* h     = ws + 204800;                // 614400
  short* h_b   = (short*)(ws + 819200);      // 1024*640 sh = 327680 f
  short* msg_b = (short*)(ws + 1146880);     // 327680 f
  short* mtmp_b= (short*)(ws + 1474560);     // 327680 f
  short* x1_b  = (short*)(ws + 1802240);     // 327680 f
  short* basis = (short*)(ws + 2129920);     // 32768 f
  short* ttab  = (short*)(ws + 2162688);     // 1966080 f
  short* wtab_b= (short*)(ws + 4128768);     // 1843200 f
  short* w1b   = (short*)(ws + 5971968);     // 122880 f
  short* nwall = (short*)(ws + 6094848);     // 4915200 f
  float* out   = (float*)d_out;

  const size_t WSZ = (size_t)WROW*WCOL;

  prolog_k<<<5152, 256, 0, stream>>>(pos, nbr, dist, cv,
      w1, basis, w1b, l1w, l2w, ilw, w2, nwall, z, emb, h, h_b, pooled);
  tabA_k<<<dim3(LL*(NKNOT/128), 5), 256, 0, stream>>>(basis, w1b, b1, ttab);
  tabB_k<<<dim3(LL*(NKNOT/128), 5), 256, 0, stream>>>(ttab, nwall, b2, wtab_b);

  dim3 gn(32, 10);
  for (int l = 0; l < LL; ++l) {
    // x1_b = bf16(h @ lin1_w[l])
    gemm_node_k<0><<<gn, 512, 0, stream>>>(h_b, nwall + (size_t)(0*6 + l)*WSZ,
        nullptr, x1_b, nullptr, nullptr);
    // msg_b[node] = bf16(sum_e C_e * Wtab(d_e) (.) x1[nbr_e])
    gather_k<<<NN, 320, 0, stream>>>(wtab_b + (size_t)l*NKNOT*HD, cv, nbr, dist, x1_b, msg_b);
    // mtmp_b = bf16(ssp(msg @ lin2_w[l] + lin2_b[l]))
    gemm_node_k<1><<<gn, 512, 0, stream>>>(msg_b, nwall + (size_t)(1*6 + l)*WSZ,
        l2b + (size_t)l*HD, mtmp_b, nullptr, nullptr);
    // h += mtmp @ int_lin_w[l] + int_lin_b[l]; h_b = bf16(h); last layer also pools
    if (l < LL-1)
      gemm_node_k<2><<<gn, 512, 0, stream>>>(mtmp_b, nwall + (size_t)(2*6 + l)*WSZ,
          ilb + (size_t)l*HD, h_b, h, nullptr);
    else
      gemm_node_k<3><<<gn, 512, 0, stream>>>(mtmp_b, nwall + (size_t)(2*6 + l)*WSZ,
          ilb + (size_t)l*HD, h_b, h, pooled);
  }
  pool_out_k<<<dim3(10, NB), 256, 0, stream>>>(pooled, pw, pb, out);
}